// Round 1
// baseline (8618.977 us; speedup 1.0000x reference)
//
#include <hip/hip_runtime.h>
#include <hip/hip_bf16.h>

// ---------- constants ----------
#define B 16
#define C 64
#define H 128
#define W 128
#define S 32
#define S2 1024
#define HW 16384

// ---------- Keys cubic kernel (a = -0.5), matches jax.image.resize 'cubic' ----------
__device__ __forceinline__ float keys(float t) {
    t = fabsf(t);
    if (t >= 2.f) return 0.f;
    float t2 = t * t, t3 = t2 * t;
    if (t >= 1.f) return -0.5f * t3 + 2.5f * t2 - 4.f * t + 2.f;
    return 1.5f * t3 - 2.5f * t2 + 1.f;
}

// ---------- kernel 0: precompute resize weights ----------
// wd[32][16]: downsample 128->32, antialias (kernel_scale=4), renormalized over valid taps
// wu[128][4]: upsample 32->128, kernel_scale=1, renormalized over valid taps
__global__ void k_init(float* __restrict__ wd, float* __restrict__ wu) {
    int tid = threadIdx.x;
    if (tid < 32) {
        int i = tid;
        float sf = 4.f * i + 1.5f;      // (i+0.5)*4 - 0.5
        int j0 = 4 * i - 6;             // 16 taps: j in [4i-6, 4i+9]
        float w[16];
        float s = 0.f;
        for (int k = 0; k < 16; k++) {
            int j = j0 + k;
            float v = 0.f;
            if (j >= 0 && j < 128) v = keys((sf - (float)j) * 0.25f);
            w[k] = v; s += v;
        }
        float inv = 1.f / s;
        for (int k = 0; k < 16; k++) wd[i * 16 + k] = w[k] * inv;
    } else if (tid >= 64 && tid < 192) {
        int i = tid - 64;
        float sf = 0.25f * i - 0.375f;
        int j0 = (int)floorf(sf) - 1;   // 4 taps
        float w[4];
        float s = 0.f;
        for (int k = 0; k < 4; k++) {
            int j = j0 + k;
            float v = 0.f;
            if (j >= 0 && j < 32) v = keys(sf - (float)j);
            w[k] = v; s += v;
        }
        float inv = 1.f / s;
        for (int k = 0; k < 4; k++) wu[i * 4 + k] = w[k] * inv;
    }
}

// ---------- kernel 1: bicubic downsample x,y -> re[2][B][C][1024] ----------
__global__ void k_down(const float* __restrict__ x, const float* __restrict__ y,
                       const float* __restrict__ wd, float* __restrict__ re) {
    int bid = blockIdx.x;               // img*1024 + b*64 + c
    int img = bid >> 10;
    int bc = bid & 1023;
    const float* src = (img ? y : x) + (size_t)bc * HW;
    __shared__ float tmp[32][128];
    __shared__ float wsh[512];
    int tid = threadIdx.x;
    for (int i = tid; i < 512; i += 256) wsh[i] = wd[i];
    __syncthreads();
    // row pass (resize along H)
    for (int idx = tid; idx < 32 * 128; idx += 256) {
        int oy = idx >> 7, xx = idx & 127;
        int j0 = 4 * oy - 6;
        float acc = 0.f;
        #pragma unroll
        for (int k = 0; k < 16; k++) {
            int j = j0 + k;
            if (j >= 0 && j < 128) acc += wsh[oy * 16 + k] * src[j * 128 + xx];
        }
        tmp[oy][xx] = acc;
    }
    __syncthreads();
    // col pass (resize along W)
    for (int idx = tid; idx < 1024; idx += 256) {
        int oy = idx >> 5, ox = idx & 31;
        int j0 = 4 * ox - 6;
        float acc = 0.f;
        #pragma unroll
        for (int k = 0; k < 16; k++) {
            int j = j0 + k;
            if (j >= 0 && j < 128) acc += wsh[ox * 16 + k] * tmp[oy][j];
        }
        re[(size_t)bid * 1024 + idx] = acc;
    }
}

// ---------- kernel 2: six QKV 3x3 convs (64->64, 32x32) + BN-fold + ReLU ----------
struct QkvArgs {
    const float* w[6];
    const float* s[6];
    const float* b[6];
};

__global__ void __launch_bounds__(256) k_qkv(const float* __restrict__ re, QkvArgs args,
                                             float* __restrict__ qkv, float* __restrict__ vt) {
    int bid = blockIdx.x;               // q*256 + b*16 + chunk   (grid 6*16*16 = 1536)
    int q = bid >> 8;
    int rem = bid & 255;
    int b = rem >> 4;
    int chunk = rem & 15;
    int co0 = chunk * 4;
    int img = (q < 3) ? 0 : 1;
    const float* src = re + ((size_t)(img * 16 + b)) * 64 * 1024;
    const float* Wt = args.w[q];
    __shared__ float sh[34 * 34];
    __shared__ float wsh[36];
    float acc[4][4] = {};               // [co][px]
    int tid = threadIdx.x;
    for (int ci = 0; ci < 64; ci++) {
        for (int idx = tid; idx < 1156; idx += 256) {
            int iy = idx / 34 - 1, ix = idx % 34 - 1;
            float v = 0.f;
            if (iy >= 0 && iy < 32 && ix >= 0 && ix < 32) v = src[ci * 1024 + iy * 32 + ix];
            sh[idx] = v;
        }
        if (tid < 36) wsh[tid] = Wt[((size_t)(co0 + tid / 9) * 64 + ci) * 9 + tid % 9];
        __syncthreads();
        #pragma unroll
        for (int i = 0; i < 4; i++) {
            int p = tid + i * 256;
            int yy = p >> 5, xx = p & 31;
            float t[9];
            #pragma unroll
            for (int dy = 0; dy < 3; dy++)
                #pragma unroll
                for (int dx = 0; dx < 3; dx++) t[dy * 3 + dx] = sh[(yy + dy) * 34 + (xx + dx)];
            #pragma unroll
            for (int co = 0; co < 4; co++) {
                float a2 = 0.f;
                #pragma unroll
                for (int k = 0; k < 9; k++) a2 += t[k] * wsh[co * 9 + k];
                acc[co][i] += a2;
            }
        }
        __syncthreads();
    }
    for (int co = 0; co < 4; co++) {
        int oc = co0 + co;
        float sc = args.s[q][oc], bb = args.b[q][oc];
        for (int i = 0; i < 4; i++) {
            int p = tid + i * 256;
            float v = fmaxf(acc[co][i] * sc + bb, 0.f);
            qkv[(((size_t)q * 16 + b) * 64 + oc) * 1024 + p] = v;
            if (q == 2) vt[((size_t)b * 1024 + p) * 64 + oc] = v;         // RVT
            if (q == 5) vt[(((size_t)(16 + b)) * 1024 + p) * 64 + oc] = v; // IVT
        }
    }
}

// ---------- kernel 3: attention (4 variants) -> ref[4][B][C][1024] ----------
__global__ void __launch_bounds__(256) k_attn(const float* __restrict__ qkv,
                                              const float* __restrict__ vt,
                                              float* __restrict__ ref) {
    int bid = blockIdx.x;               // a*2048 + b*128 + sb   (grid 4*16*128 = 8192)
    int a = bid >> 11;
    int rem = bid & 2047;
    int b = rem >> 7;
    int sb = rem & 127;
    int s0 = sb * 8;
    const int qi[4] = {0, 3, 0, 3};
    const int ki[4] = {1, 4, 4, 1};
    const float* Q = qkv + ((size_t)(qi[a] * 16 + b)) * 64 * 1024;
    const float* K = qkv + ((size_t)(ki[a] * 16 + b)) * 64 * 1024;
    __shared__ float sc[8][1024];
    __shared__ float kb[64][8];
    __shared__ float part[4][8][64];
    __shared__ float invs[8];
    int tid = threadIdx.x;
    for (int idx = tid; idx < 512; idx += 256) {
        int c = idx >> 3, si = idx & 7;
        kb[c][si] = K[c * 1024 + s0 + si];
    }
    __syncthreads();
    // scores: sc[si][t] = sum_c K[c,s0+si] * Q[c,t]
    {
        float acc[4][8] = {};
        for (int c = 0; c < 64; c++) {
            float kv[8];
            #pragma unroll
            for (int si = 0; si < 8; si++) kv[si] = kb[c][si];
            float qv[4];
            #pragma unroll
            for (int k = 0; k < 4; k++) qv[k] = Q[c * 1024 + tid + k * 256];
            #pragma unroll
            for (int k = 0; k < 4; k++)
                #pragma unroll
                for (int si = 0; si < 8; si++) acc[k][si] += qv[k] * kv[si];
        }
        #pragma unroll
        for (int k = 0; k < 4; k++)
            #pragma unroll
            for (int si = 0; si < 8; si++) sc[si][tid + k * 256] = acc[k][si];
    }
    __syncthreads();
    // softmax per row (32 lanes per row)
    {
        int si = tid >> 5, l = tid & 31;
        float mx = -1e30f;
        for (int m = 0; m < 32; m++) mx = fmaxf(mx, sc[si][m * 32 + l]);
        for (int off = 16; off; off >>= 1) mx = fmaxf(mx, __shfl_xor(mx, off, 32));
        float sum = 0.f;
        for (int m = 0; m < 32; m++) {
            float e = expf(sc[si][m * 32 + l] - mx);
            sc[si][m * 32 + l] = e;
            sum += e;
        }
        for (int off = 16; off; off >>= 1) sum += __shfl_xor(sum, off, 32);
        if (l == 0) invs[si] = 1.f / sum;
    }
    __syncthreads();
    // PV: refine[c, s0+si] = invs[si] * sum_t V[c,t] * e[si,t]
    int c = tid & 63, grp = tid >> 6;
    const float* rvt = vt + (size_t)b * 1024 * 64;
    const float* ivt = vt + (size_t)(16 + b) * 1024 * 64;
    const float* v1 = (a == 3) ? ivt : rvt;   // a<2: rvt+ivt, a==2: rvt, a==3: ivt
    const float* v2 = (a < 2) ? ivt : nullptr;
    float acc[8] = {};
    for (int t0 = grp * 256; t0 < grp * 256 + 256; t0 += 4) {
        float v[4];
        #pragma unroll
        for (int j = 0; j < 4; j++) {
            int t = t0 + j;
            float vv = v1[t * 64 + c];
            if (v2) vv += v2[t * 64 + c];
            v[j] = vv;
        }
        #pragma unroll
        for (int si = 0; si < 8; si++) {
            float4 s4 = *reinterpret_cast<const float4*>(&sc[si][t0]);
            acc[si] += v[0] * s4.x + v[1] * s4.y + v[2] * s4.z + v[3] * s4.w;
        }
    }
    #pragma unroll
    for (int si = 0; si < 8; si++) part[grp][si][c] = acc[si];
    __syncthreads();
    for (int idx = tid; idx < 512; idx += 256) {
        int si = idx >> 6, cc = idx & 63;
        float v = (part[0][si][cc] + part[1][si][cc] + part[2][si][cc] + part[3][si][cc]) * invs[si];
        ref[(((size_t)a * 16 + b) * 64 + cc) * 1024 + s0 + si] = v;
    }
}

// ---------- kernel 4: bicubic upsample + g*refine + orig -> cat4 (bf16) ----------
__global__ void k_up(const float* __restrict__ ref, const float* __restrict__ wu,
                     const float* __restrict__ x, const float* __restrict__ y,
                     const float* __restrict__ g1, const float* __restrict__ g2,
                     const float* __restrict__ g3, const float* __restrict__ g4,
                     __hip_bfloat16* __restrict__ cat4) {
    int bid = blockIdx.x;               // a*1024 + b*64 + c  (grid 4096)
    int a = bid >> 10;
    int rem = bid & 1023;
    int b = rem >> 6, c = rem & 63;
    const float* src = ref + (size_t)bid * 1024;
    const float* orig = ((a == 0 || a == 3) ? x : y) + (size_t)(b * 64 + c) * HW;
    float gv = (a == 0 ? g1 : a == 1 ? g2 : a == 2 ? g3 : g4)[0];
    __shared__ float rch[1024];
    __shared__ float tmp[128][32];
    __shared__ float wsh[512];
    int tid = threadIdx.x;
    for (int i = tid; i < 512; i += 256) wsh[i] = wu[i];
    for (int i = tid; i < 1024; i += 256) rch[i] = src[i];
    __syncthreads();
    // rows: 32 -> 128 along y
    for (int idx = tid; idx < 128 * 32; idx += 256) {
        int oy = idx >> 5, xx = idx & 31;
        float sf = 0.25f * oy - 0.375f;
        int j0 = (int)floorf(sf) - 1;
        float acc = 0.f;
        #pragma unroll
        for (int k = 0; k < 4; k++) {
            int j = j0 + k;
            if (j >= 0 && j < 32) acc += wsh[oy * 4 + k] * rch[j * 32 + xx];
        }
        tmp[oy][xx] = acc;
    }
    __syncthreads();
    size_t obase = ((size_t)b * 256 + a * 64 + c) * HW;
    for (int idx = tid; idx < HW; idx += 256) {
        int oy = idx >> 7, ox = idx & 127;
        float sf = 0.25f * ox - 0.375f;
        int j0 = (int)floorf(sf) - 1;
        float acc = 0.f;
        #pragma unroll
        for (int k = 0; k < 4; k++) {
            int j = j0 + k;
            if (j >= 0 && j < 32) acc += wsh[ox * 4 + k] * tmp[oy][j];
        }
        float v = gv * acc + orig[idx];
        cat4[obase + idx] = __float2bfloat16(v);
    }
}

// ---------- kernel 5: channel mean/max for spatial attention ----------
__global__ void k_mm(const float* __restrict__ x, const float* __restrict__ y,
                     float* __restrict__ mm) {
    int bid = blockIdx.x;               // img*128 + b*8 + chunk (grid 256)
    int img = bid >> 7;
    int rem = bid & 127;
    int b = rem >> 3;
    int chunk = rem & 7;
    const float* src = (img ? y : x) + (size_t)b * 64 * HW;
    int tid = threadIdx.x;
    size_t base = ((size_t)(img * 16 + b)) * 2 * HW;
    for (int i = 0; i < 8; i++) {
        int px = chunk * 2048 + i * 256 + tid;
        float s = 0.f, mx = -1e30f;
        for (int c = 0; c < 64; c++) {
            float v = src[(size_t)c * HW + px];
            s += v;
            mx = fmaxf(mx, v);
        }
        mm[base + px] = s * (1.f / 64.f);
        mm[base + HW + px] = mx;
    }
}

// ---------- kernel 6: spatial-attention conv + sigmoid -> sig[2][B][HW] ----------
__global__ void k_spaconv(const float* __restrict__ mm, const float* __restrict__ saw_r,
                          const float* __restrict__ saw_i, float* __restrict__ sig) {
    int bid = blockIdx.x;               // img*128 + b*8 + chunk (grid 256)
    int img = bid >> 7;
    int rem = bid & 127;
    int b = rem >> 3;
    int chunk = rem & 7;
    const float* w = img ? saw_i : saw_r;
    __shared__ float wsh[18];
    if (threadIdx.x < 18) wsh[threadIdx.x] = w[threadIdx.x];
    __syncthreads();
    const float* m0 = mm + ((size_t)(img * 16 + b)) * 2 * HW;
    for (int i = 0; i < 8; i++) {
        int px = chunk * 2048 + i * 256 + threadIdx.x;
        int yy = px >> 7, xx = px & 127;
        float acc = 0.f;
        #pragma unroll
        for (int ch = 0; ch < 2; ch++) {
            const float* m = m0 + (size_t)ch * HW;
            #pragma unroll
            for (int dy = 0; dy < 3; dy++)
                #pragma unroll
                for (int dx = 0; dx < 3; dx++) {
                    int iy = yy + dy - 1, ix = xx + dx - 1;
                    if (iy >= 0 && iy < 128 && ix >= 0 && ix < 128)
                        acc += wsh[ch * 9 + dy * 3 + dx] * m[iy * 128 + ix];
                }
        }
        sig[((size_t)(img * 16 + b)) * HW + px] = 1.f / (1.f + expf(-acc));
    }
}

// ---------- kernel 7: red conv (256->64, 128x128) + BN + ReLU -> gatt (bf16) ----------
__global__ void __launch_bounds__(256) k_red(const __hip_bfloat16* __restrict__ cat4,
                                             const float* __restrict__ rw,
                                             const float* __restrict__ rs,
                                             const float* __restrict__ rb,
                                             __hip_bfloat16* __restrict__ gatt) {
    int bid = blockIdx.x;               // b*128 + cochunk*16 + tile (grid 2048)
    int b = bid >> 7;
    int rem = bid & 127;
    int cochunk = rem >> 4;
    int tile = rem & 15;
    int co0 = cochunk * 8;
    int ty0 = (tile >> 2) * 32, tx0 = (tile & 3) * 32;
    __shared__ float sh[34 * 34];
    __shared__ float wsh[72];
    float acc[8][4] = {};
    int tid = threadIdx.x;
    const __hip_bfloat16* src = cat4 + (size_t)b * 256 * HW;
    for (int ci = 0; ci < 256; ci++) {
        for (int idx = tid; idx < 1156; idx += 256) {
            int iy = ty0 + idx / 34 - 1, ix = tx0 + idx % 34 - 1;
            float v = 0.f;
            if (iy >= 0 && iy < 128 && ix >= 0 && ix < 128)
                v = __bfloat162float(src[(size_t)ci * HW + iy * 128 + ix]);
            sh[idx] = v;
        }
        for (int idx = tid; idx < 72; idx += 256)
            wsh[idx] = rw[((size_t)(co0 + idx / 9) * 256 + ci) * 9 + idx % 9];
        __syncthreads();
        #pragma unroll
        for (int i = 0; i < 4; i++) {
            int p = tid + i * 256;
            int yy = p >> 5, xx = p & 31;
            float t[9];
            #pragma unroll
            for (int dy = 0; dy < 3; dy++)
                #pragma unroll
                for (int dx = 0; dx < 3; dx++) t[dy * 3 + dx] = sh[(yy + dy) * 34 + (xx + dx)];
            #pragma unroll
            for (int co = 0; co < 8; co++) {
                float a2 = 0.f;
                #pragma unroll
                for (int k = 0; k < 9; k++) a2 += t[k] * wsh[co * 9 + k];
                acc[co][i] += a2;
            }
        }
        __syncthreads();
    }
    for (int co = 0; co < 8; co++) {
        int oc = co0 + co;
        float s = rs[oc], bb = rb[oc];
        for (int i = 0; i < 4; i++) {
            int p = tid + i * 256;
            int yy = p >> 5, xx = p & 31;
            float v = fmaxf(acc[co][i] * s + bb, 0.f);
            gatt[((size_t)b * 64 + oc) * HW + (ty0 + yy) * 128 + (tx0 + xx)] = __float2bfloat16(v);
        }
    }
}

// ---------- kernel 8: sec conv (192->64, 128x128) + BN + ReLU -> out (fp32) ----------
// input channels: [0,64): gatt ; [64,128): y*(1+sig_inf) ; [128,192): x*(1+sig_rgb)
__global__ void __launch_bounds__(256) k_sec(const __hip_bfloat16* __restrict__ gatt,
                                             const float* __restrict__ xin,
                                             const float* __restrict__ yin,
                                             const float* __restrict__ sig,
                                             const float* __restrict__ sw,
                                             const float* __restrict__ ss,
                                             const float* __restrict__ sb,
                                             float* __restrict__ out) {
    int bid = blockIdx.x;               // b*128 + cochunk*16 + tile (grid 2048)
    int b = bid >> 7;
    int rem = bid & 127;
    int cochunk = rem >> 4;
    int tile = rem & 15;
    int co0 = cochunk * 8;
    int ty0 = (tile >> 2) * 32, tx0 = (tile & 3) * 32;
    __shared__ float sh[34 * 34];
    __shared__ float wsh[72];
    __shared__ float sigr[34 * 34];
    __shared__ float sigi[34 * 34];
    int tid = threadIdx.x;
    for (int idx = tid; idx < 1156; idx += 256) {
        int iy = ty0 + idx / 34 - 1, ix = tx0 + idx % 34 - 1;
        float sr = 0.f, si = 0.f;
        if (iy >= 0 && iy < 128 && ix >= 0 && ix < 128) {
            sr = 1.f + sig[((size_t)(0 * 16 + b)) * HW + iy * 128 + ix];
            si = 1.f + sig[((size_t)(1 * 16 + b)) * HW + iy * 128 + ix];
        }
        sigr[idx] = sr;
        sigi[idx] = si;
    }
    __syncthreads();
    float acc[8][4] = {};
    for (int ci = 0; ci < 192; ci++) {
        for (int idx = tid; idx < 1156; idx += 256) {
            int iy = ty0 + idx / 34 - 1, ix = tx0 + idx % 34 - 1;
            float v = 0.f;
            if (iy >= 0 && iy < 128 && ix >= 0 && ix < 128) {
                if (ci < 64)
                    v = __bfloat162float(gatt[((size_t)b * 64 + ci) * HW + iy * 128 + ix]);
                else if (ci < 128)
                    v = yin[((size_t)b * 64 + (ci - 64)) * HW + iy * 128 + ix] * sigi[idx];
                else
                    v = xin[((size_t)b * 64 + (ci - 128)) * HW + iy * 128 + ix] * sigr[idx];
            }
            sh[idx] = v;
        }
        for (int idx = tid; idx < 72; idx += 256)
            wsh[idx] = sw[((size_t)(co0 + idx / 9) * 192 + ci) * 9 + idx % 9];
        __syncthreads();
        #pragma unroll
        for (int i = 0; i < 4; i++) {
            int p = tid + i * 256;
            int yy = p >> 5, xx = p & 31;
            float t[9];
            #pragma unroll
            for (int dy = 0; dy < 3; dy++)
                #pragma unroll
                for (int dx = 0; dx < 3; dx++) t[dy * 3 + dx] = sh[(yy + dy) * 34 + (xx + dx)];
            #pragma unroll
            for (int co = 0; co < 8; co++) {
                float a2 = 0.f;
                #pragma unroll
                for (int k = 0; k < 9; k++) a2 += t[k] * wsh[co * 9 + k];
                acc[co][i] += a2;
            }
        }
        __syncthreads();
    }
    for (int co = 0; co < 8; co++) {
        int oc = co0 + co;
        float s = ss[oc], bb = sb[oc];
        for (int i = 0; i < 4; i++) {
            int p = tid + i * 256;
            int yy = p >> 5, xx = p & 31;
            float v = fmaxf(acc[co][i] * s + bb, 0.f);
            out[((size_t)b * 64 + oc) * HW + (ty0 + yy) * 128 + (tx0 + xx)] = v;
        }
    }
}

// ---------- launch ----------
extern "C" void kernel_launch(void* const* d_in, const int* in_sizes, int n_in,
                              void* d_out, int out_size, void* d_ws, size_t ws_size,
                              hipStream_t stream) {
    const float* x = (const float*)d_in[0];
    const float* y = (const float*)d_in[1];

    QkvArgs qa;
    for (int q = 0; q < 6; q++) {
        qa.w[q] = (const float*)d_in[2 + 3 * q];
        qa.s[q] = (const float*)d_in[3 + 3 * q];
        qa.b[q] = (const float*)d_in[4 + 3 * q];
    }
    const float* red_w = (const float*)d_in[20];
    const float* red_s = (const float*)d_in[21];
    const float* red_b = (const float*)d_in[22];
    const float* sec_w = (const float*)d_in[23];
    const float* sec_s = (const float*)d_in[24];
    const float* sec_b = (const float*)d_in[25];
    const float* g1 = (const float*)d_in[26];
    const float* g2 = (const float*)d_in[27];
    const float* g3 = (const float*)d_in[28];
    const float* g4 = (const float*)d_in[29];
    const float* sa_r_w = (const float*)d_in[30];
    const float* sa_i_w = (const float*)d_in[31];

    // workspace layout (floats, then bf16)
    float* ws = (float*)d_ws;
    float* WD = ws;                                  // 512
    float* WU = WD + 512;                            // 512
    float* RE = WU + 512;                            // 2*16*64*1024 = 2,097,152
    float* QKV = RE + 2097152;                       // 6*16*64*1024 = 6,291,456
    float* VT = QKV + 6291456;                       // 2*16*1024*64 = 2,097,152
    float* REF = VT + 2097152;                       // 4*16*64*1024 = 4,194,304
    float* MM = REF + 4194304;                       // 2*16*2*16384 = 1,048,576
    float* SIG = MM + 1048576;                       // 2*16*16384   =   524,288
    __hip_bfloat16* CAT4 = (__hip_bfloat16*)(SIG + 524288);  // 16*256*16384 bf16
    __hip_bfloat16* GATT = CAT4 + (size_t)16 * 256 * 16384;  // 16*64*16384 bf16

    k_init<<<1, 256, 0, stream>>>(WD, WU);
    k_down<<<2 * 16 * 64, 256, 0, stream>>>(x, y, WD, RE);
    k_qkv<<<6 * 16 * 16, 256, 0, stream>>>(RE, qa, QKV, VT);
    k_attn<<<4 * 16 * 128, 256, 0, stream>>>(QKV, VT, REF);
    k_up<<<4 * 16 * 64, 256, 0, stream>>>(REF, WU, x, y, g1, g2, g3, g4, CAT4);
    k_mm<<<2 * 16 * 8, 256, 0, stream>>>(x, y, MM);
    k_spaconv<<<2 * 16 * 8, 256, 0, stream>>>(MM, sa_r_w, sa_i_w, SIG);
    k_red<<<16 * 128, 256, 0, stream>>>(CAT4, red_w, red_s, red_b, GATT);
    k_sec<<<16 * 128, 256, 0, stream>>>(GATT, x, y, SIG, sec_w, sec_s, sec_b, (float*)d_out);
}

// Round 2
// 1670.111 us; speedup vs baseline: 5.1607x; 5.1607x over previous
//
#include <hip/hip_runtime.h>
#include <hip/hip_bf16.h>

// ---------- constants ----------
#define B 16
#define C 64
#define H 128
#define W 128
#define S 32
#define S2 1024
#define HW 16384

typedef __attribute__((ext_vector_type(8))) short bf16x8;
typedef __attribute__((ext_vector_type(4))) float f32x4;
typedef __attribute__((ext_vector_type(8))) unsigned short u16x8;
typedef __attribute__((ext_vector_type(4))) unsigned short u16x4;

static __device__ __forceinline__ unsigned short f2bf(float v) {
    __hip_bfloat16 h = __float2bfloat16(v);
    return *reinterpret_cast<unsigned short*>(&h);
}

// ---------- Keys cubic kernel (a = -0.5), matches jax.image.resize 'cubic' ----------
__device__ __forceinline__ float keys(float t) {
    t = fabsf(t);
    if (t >= 2.f) return 0.f;
    float t2 = t * t, t3 = t2 * t;
    if (t >= 1.f) return -0.5f * t3 + 2.5f * t2 - 4.f * t + 2.f;
    return 1.5f * t3 - 2.5f * t2 + 1.f;
}

// ---------- kernel 0: precompute resize weights ----------
__global__ void k_init(float* __restrict__ wd, float* __restrict__ wu) {
    int tid = threadIdx.x;
    if (tid < 32) {
        int i = tid;
        float sf = 4.f * i + 1.5f;
        int j0 = 4 * i - 6;
        float w[16];
        float s = 0.f;
        for (int k = 0; k < 16; k++) {
            int j = j0 + k;
            float v = 0.f;
            if (j >= 0 && j < 128) v = keys((sf - (float)j) * 0.25f);
            w[k] = v; s += v;
        }
        float inv = 1.f / s;
        for (int k = 0; k < 16; k++) wd[i * 16 + k] = w[k] * inv;
    } else if (tid >= 64 && tid < 192) {
        int i = tid - 64;
        float sf = 0.25f * i - 0.375f;
        int j0 = (int)floorf(sf) - 1;
        float w[4];
        float s = 0.f;
        for (int k = 0; k < 4; k++) {
            int j = j0 + k;
            float v = 0.f;
            if (j >= 0 && j < 32) v = keys(sf - (float)j);
            w[k] = v; s += v;
        }
        float inv = 1.f / s;
        for (int k = 0; k < 4; k++) wu[i * 4 + k] = w[k] * inv;
    }
}

// ---------- kernel 1: bicubic downsample x,y -> re[2][B][C][1024] ----------
__global__ void k_down(const float* __restrict__ x, const float* __restrict__ y,
                       const float* __restrict__ wd, float* __restrict__ re) {
    int bid = blockIdx.x;
    int img = bid >> 10;
    int bc = bid & 1023;
    const float* src = (img ? y : x) + (size_t)bc * HW;
    __shared__ float tmp[32][128];
    __shared__ float wsh[512];
    int tid = threadIdx.x;
    for (int i = tid; i < 512; i += 256) wsh[i] = wd[i];
    __syncthreads();
    for (int idx = tid; idx < 32 * 128; idx += 256) {
        int oy = idx >> 7, xx = idx & 127;
        int j0 = 4 * oy - 6;
        float acc = 0.f;
        #pragma unroll
        for (int k = 0; k < 16; k++) {
            int j = j0 + k;
            if (j >= 0 && j < 128) acc += wsh[oy * 16 + k] * src[j * 128 + xx];
        }
        tmp[oy][xx] = acc;
    }
    __syncthreads();
    for (int idx = tid; idx < 1024; idx += 256) {
        int oy = idx >> 5, ox = idx & 31;
        int j0 = 4 * ox - 6;
        float acc = 0.f;
        #pragma unroll
        for (int k = 0; k < 16; k++) {
            int j = j0 + k;
            if (j >= 0 && j < 128) acc += wsh[ox * 16 + k] * tmp[oy][j];
        }
        re[(size_t)bid * 1024 + idx] = acc;
    }
}

// ---------- kernel 2: six QKV 3x3 convs (64->64, 32x32) ----------
struct QkvArgs {
    const float* w[6];
    const float* s[6];
    const float* b[6];
};

__global__ void __launch_bounds__(256) k_qkv(const float* __restrict__ re, QkvArgs args,
                                             float* __restrict__ qkv, float* __restrict__ vt) {
    int bid = blockIdx.x;
    int q = bid >> 8;
    int rem = bid & 255;
    int b = rem >> 4;
    int chunk = rem & 15;
    int co0 = chunk * 4;
    int img = (q < 3) ? 0 : 1;
    const float* src = re + ((size_t)(img * 16 + b)) * 64 * 1024;
    const float* Wt = args.w[q];
    __shared__ float sh[34 * 34];
    __shared__ float wsh[36];
    float acc[4][4] = {};
    int tid = threadIdx.x;
    for (int ci = 0; ci < 64; ci++) {
        for (int idx = tid; idx < 1156; idx += 256) {
            int iy = idx / 34 - 1, ix = idx % 34 - 1;
            float v = 0.f;
            if (iy >= 0 && iy < 32 && ix >= 0 && ix < 32) v = src[ci * 1024 + iy * 32 + ix];
            sh[idx] = v;
        }
        if (tid < 36) wsh[tid] = Wt[((size_t)(co0 + tid / 9) * 64 + ci) * 9 + tid % 9];
        __syncthreads();
        #pragma unroll
        for (int i = 0; i < 4; i++) {
            int p = tid + i * 256;
            int yy = p >> 5, xx = p & 31;
            float t[9];
            #pragma unroll
            for (int dy = 0; dy < 3; dy++)
                #pragma unroll
                for (int dx = 0; dx < 3; dx++) t[dy * 3 + dx] = sh[(yy + dy) * 34 + (xx + dx)];
            #pragma unroll
            for (int co = 0; co < 4; co++) {
                float a2 = 0.f;
                #pragma unroll
                for (int k = 0; k < 9; k++) a2 += t[k] * wsh[co * 9 + k];
                acc[co][i] += a2;
            }
        }
        __syncthreads();
    }
    for (int co = 0; co < 4; co++) {
        int oc = co0 + co;
        float sc = args.s[q][oc], bb = args.b[q][oc];
        for (int i = 0; i < 4; i++) {
            int p = tid + i * 256;
            float v = fmaxf(acc[co][i] * sc + bb, 0.f);
            qkv[(((size_t)q * 16 + b) * 64 + oc) * 1024 + p] = v;
            if (q == 2) vt[((size_t)b * 1024 + p) * 64 + oc] = v;
            if (q == 5) vt[(((size_t)(16 + b)) * 1024 + p) * 64 + oc] = v;
        }
    }
}

// ---------- kernel 3: attention (4 variants) -> ref[4][B][C][1024] ----------
__global__ void __launch_bounds__(256) k_attn(const float* __restrict__ qkv,
                                              const float* __restrict__ vt,
                                              float* __restrict__ ref) {
    int bid = blockIdx.x;
    int a = bid >> 11;
    int rem = bid & 2047;
    int b = rem >> 7;
    int sb = rem & 127;
    int s0 = sb * 8;
    const int qi[4] = {0, 3, 0, 3};
    const int ki[4] = {1, 4, 4, 1};
    const float* Q = qkv + ((size_t)(qi[a] * 16 + b)) * 64 * 1024;
    const float* K = qkv + ((size_t)(ki[a] * 16 + b)) * 64 * 1024;
    __shared__ float sc[8][1024];
    __shared__ float kb[64][8];
    __shared__ float part[4][8][64];
    __shared__ float invs[8];
    int tid = threadIdx.x;
    for (int idx = tid; idx < 512; idx += 256) {
        int c = idx >> 3, si = idx & 7;
        kb[c][si] = K[c * 1024 + s0 + si];
    }
    __syncthreads();
    {
        float acc[4][8] = {};
        for (int c = 0; c < 64; c++) {
            float kv[8];
            #pragma unroll
            for (int si = 0; si < 8; si++) kv[si] = kb[c][si];
            float qv[4];
            #pragma unroll
            for (int k = 0; k < 4; k++) qv[k] = Q[c * 1024 + tid + k * 256];
            #pragma unroll
            for (int k = 0; k < 4; k++)
                #pragma unroll
                for (int si = 0; si < 8; si++) acc[k][si] += qv[k] * kv[si];
        }
        #pragma unroll
        for (int k = 0; k < 4; k++)
            #pragma unroll
            for (int si = 0; si < 8; si++) sc[si][tid + k * 256] = acc[k][si];
    }
    __syncthreads();
    {
        int si = tid >> 5, l = tid & 31;
        float mx = -1e30f;
        for (int m = 0; m < 32; m++) mx = fmaxf(mx, sc[si][m * 32 + l]);
        for (int off = 16; off; off >>= 1) mx = fmaxf(mx, __shfl_xor(mx, off, 32));
        float sum = 0.f;
        for (int m = 0; m < 32; m++) {
            float e = expf(sc[si][m * 32 + l] - mx);
            sc[si][m * 32 + l] = e;
            sum += e;
        }
        for (int off = 16; off; off >>= 1) sum += __shfl_xor(sum, off, 32);
        if (l == 0) invs[si] = 1.f / sum;
    }
    __syncthreads();
    int c = tid & 63, grp = tid >> 6;
    const float* rvt = vt + (size_t)b * 1024 * 64;
    const float* ivt = vt + (size_t)(16 + b) * 1024 * 64;
    const float* v1 = (a == 3) ? ivt : rvt;
    const float* v2 = (a < 2) ? ivt : nullptr;
    float acc[8] = {};
    for (int t0 = grp * 256; t0 < grp * 256 + 256; t0 += 4) {
        float v[4];
        #pragma unroll
        for (int j = 0; j < 4; j++) {
            int t = t0 + j;
            float vv = v1[t * 64 + c];
            if (v2) vv += v2[t * 64 + c];
            v[j] = vv;
        }
        #pragma unroll
        for (int si = 0; si < 8; si++) {
            float4 s4 = *reinterpret_cast<const float4*>(&sc[si][t0]);
            acc[si] += v[0] * s4.x + v[1] * s4.y + v[2] * s4.z + v[3] * s4.w;
        }
    }
    #pragma unroll
    for (int si = 0; si < 8; si++) part[grp][si][c] = acc[si];
    __syncthreads();
    for (int idx = tid; idx < 512; idx += 256) {
        int si = idx >> 6, cc = idx & 63;
        float v = (part[0][si][cc] + part[1][si][cc] + part[2][si][cc] + part[3][si][cc]) * invs[si];
        ref[(((size_t)a * 16 + b) * 64 + cc) * 1024 + s0 + si] = v;
    }
}

// ---------- kernel 4: bicubic upsample + g*refine + orig -> cat4 (bf16) ----------
__global__ void k_up(const float* __restrict__ ref, const float* __restrict__ wu,
                     const float* __restrict__ x, const float* __restrict__ y,
                     const float* __restrict__ g1, const float* __restrict__ g2,
                     const float* __restrict__ g3, const float* __restrict__ g4,
                     __hip_bfloat16* __restrict__ cat4) {
    int bid = blockIdx.x;
    int a = bid >> 10;
    int rem = bid & 1023;
    int b = rem >> 6, c = rem & 63;
    const float* src = ref + (size_t)bid * 1024;
    const float* orig = ((a == 0 || a == 3) ? x : y) + (size_t)(b * 64 + c) * HW;
    float gv = (a == 0 ? g1 : a == 1 ? g2 : a == 2 ? g3 : g4)[0];
    __shared__ float rch[1024];
    __shared__ float tmp[128][32];
    __shared__ float wsh[512];
    int tid = threadIdx.x;
    for (int i = tid; i < 512; i += 256) wsh[i] = wu[i];
    for (int i = tid; i < 1024; i += 256) rch[i] = src[i];
    __syncthreads();
    for (int idx = tid; idx < 128 * 32; idx += 256) {
        int oy = idx >> 5, xx = idx & 31;
        float sf = 0.25f * oy - 0.375f;
        int j0 = (int)floorf(sf) - 1;
        float acc = 0.f;
        #pragma unroll
        for (int k = 0; k < 4; k++) {
            int j = j0 + k;
            if (j >= 0 && j < 32) acc += wsh[oy * 4 + k] * rch[j * 32 + xx];
        }
        tmp[oy][xx] = acc;
    }
    __syncthreads();
    size_t obase = ((size_t)b * 256 + a * 64 + c) * HW;
    for (int idx = tid; idx < HW; idx += 256) {
        int oy = idx >> 7, ox = idx & 127;
        float sf = 0.25f * ox - 0.375f;
        int j0 = (int)floorf(sf) - 1;
        float acc = 0.f;
        #pragma unroll
        for (int k = 0; k < 4; k++) {
            int j = j0 + k;
            if (j >= 0 && j < 32) acc += wsh[ox * 4 + k] * tmp[oy][j];
        }
        float v = gv * acc + orig[idx];
        cat4[obase + idx] = __float2bfloat16(v);
    }
}

// ---------- kernel 5: channel mean/max ----------
__global__ void k_mm(const float* __restrict__ x, const float* __restrict__ y,
                     float* __restrict__ mm) {
    int bid = blockIdx.x;
    int img = bid >> 7;
    int rem = bid & 127;
    int b = rem >> 3;
    int chunk = rem & 7;
    const float* src = (img ? y : x) + (size_t)b * 64 * HW;
    int tid = threadIdx.x;
    size_t base = ((size_t)(img * 16 + b)) * 2 * HW;
    for (int i = 0; i < 8; i++) {
        int px = chunk * 2048 + i * 256 + tid;
        float s = 0.f, mx = -1e30f;
        for (int c = 0; c < 64; c++) {
            float v = src[(size_t)c * HW + px];
            s += v;
            mx = fmaxf(mx, v);
        }
        mm[base + px] = s * (1.f / 64.f);
        mm[base + HW + px] = mx;
    }
}

// ---------- kernel 6: spatial-attention conv + sigmoid ----------
__global__ void k_spaconv(const float* __restrict__ mm, const float* __restrict__ saw_r,
                          const float* __restrict__ saw_i, float* __restrict__ sig) {
    int bid = blockIdx.x;
    int img = bid >> 7;
    int rem = bid & 127;
    int b = rem >> 3;
    int chunk = rem & 7;
    const float* w = img ? saw_i : saw_r;
    __shared__ float wsh[18];
    if (threadIdx.x < 18) wsh[threadIdx.x] = w[threadIdx.x];
    __syncthreads();
    const float* m0 = mm + ((size_t)(img * 16 + b)) * 2 * HW;
    for (int i = 0; i < 8; i++) {
        int px = chunk * 2048 + i * 256 + threadIdx.x;
        int yy = px >> 7, xx = px & 127;
        float acc = 0.f;
        #pragma unroll
        for (int ch = 0; ch < 2; ch++) {
            const float* m = m0 + (size_t)ch * HW;
            #pragma unroll
            for (int dy = 0; dy < 3; dy++)
                #pragma unroll
                for (int dx = 0; dx < 3; dx++) {
                    int iy = yy + dy - 1, ix = xx + dx - 1;
                    if (iy >= 0 && iy < 128 && ix >= 0 && ix < 128)
                        acc += wsh[ch * 9 + dy * 3 + dx] * m[iy * 128 + ix];
                }
        }
        sig[((size_t)(img * 16 + b)) * HW + px] = 1.f / (1.f + expf(-acc));
    }
}

// ---------- kernel 7: weight pack (BN scale folded) into MFMA A-fragment order ----------
// wpk[ks][ct][lane][j] : ks = cb*9 + ky*3 + kx ; A[m=ct*16+(lane&15)][k=(lane>>4)*4+(j&3)+16*(j>>2)]
__global__ void k_wpack(const float* __restrict__ w, const float* __restrict__ s,
                        unsigned short* __restrict__ wpk, int cin) {
    int ks = blockIdx.x;
    int tid = threadIdx.x;
    int lane = tid & 63, ct = tid >> 6;
    int cb = ks / 9, kk = ks % 9;
    int m = ct * 16 + (lane & 15);
    int qq = lane >> 4;
    float sc = s[m];
    u16x8 outv;
    #pragma unroll
    for (int j = 0; j < 8; ++j) {
        int k = qq * 4 + (j & 3) + ((j >> 2) << 4);
        int ci = cb * 32 + k;
        float v = w[((size_t)m * cin + ci) * 9 + kk] * sc;
        outv[j] = f2bf(v);
    }
    *reinterpret_cast<u16x8*>(wpk + ((size_t)(ks * 4 + ct) * 64 + lane) * 8) = outv;
}

// ---------- kernel 8: scale inputs for sec conv: sxy[b][0..63]=y*(1+sig_inf), [64..127]=x*(1+sig_rgb) ----------
__global__ void k_scale(const float* __restrict__ x, const float* __restrict__ y,
                        const float* __restrict__ sig, unsigned short* __restrict__ sxy) {
    int gid = blockIdx.x * 256 + threadIdx.x;
    int part = gid >> 21;               // 0: y*(1+sig_i), 1: x*(1+sig_r)
    int b = (gid >> 17) & 15;
    int c = (gid >> 11) & 63;
    int t8 = gid & 2047;
    int px = t8 * 8;
    const float* src = (part ? x : y) + ((size_t)b * 64 + c) * HW + px;
    const float* sg = sig + ((size_t)((part ? 0 : 16) + b)) * HW + px;
    u16x8 o;
    #pragma unroll
    for (int j = 0; j < 8; ++j) o[j] = f2bf(src[j] * (1.f + sg[j]));
    *reinterpret_cast<u16x8*>(sxy + ((size_t)b * 128 + part * 64 + c) * HW + px) = o;
}

// ---------- kernel 9: generic 3x3 conv via MFMA implicit GEMM ----------
// Cout=64. Input bf16 [b][CIN][HW] split across srcA (ci<cinA) and srcB.
// Block: 2 rows x 128 cols, 4 waves; wave tile 64co x 64px via 4x4 mfma_f32_16x16x32_bf16.
template<int CIBLKS, bool OBF16>
__global__ void __launch_bounds__(256) k_conv(const unsigned short* __restrict__ srcA, int cinA,
                                              const unsigned short* __restrict__ srcB,
                                              const unsigned short* __restrict__ wpk,
                                              const float* __restrict__ bias,
                                              void* __restrict__ outp, int outcTot) {
    const int CIN = CIBLKS * 32;
    const int cinB = CIN - cinA;
    int bid = blockIdx.x;
    int b = bid >> 6, rp = bid & 63;
    int y0 = rp * 2;
    int tid = threadIdx.x;
    int lane = tid & 63, w = tid >> 6;
    int qg = lane >> 4;                 // k-group 0..3
    int l15 = lane & 15;

    __shared__ __align__(16) unsigned short xs[4 * 132 * 32];   // [row][col][slot]

    f32x4 acc[4][4] = {};               // [ct(co)][nt(px)]

    // zero halo cols 0 and 129 (never overwritten; persists across ci-blocks)
    if (tid < 64) {
        int r = tid >> 4;
        int rem = tid & 15;
        int col = (rem >> 3) ? 129 : 0;
        int qd = rem & 7;
        int sb = ((qd & 3) << 3) + ((qd >> 2) << 2);
        int sbs = sb ^ (((col >> 1) & 3) << 3);
        u16x4 z = {0, 0, 0, 0};
        *reinterpret_cast<u16x4*>(&xs[(r * 132 + col) * 32 + sbs]) = z;
    }

    const bf16x8* wp = reinterpret_cast<const bf16x8*>(wpk);
    int colb = ((w & 1) << 6) + l15;    // output col base + lane offset
    int wr = w >> 1;                    // output row within pair

    for (int cb = 0; cb < CIBLKS; ++cb) {
        __syncthreads();
        // ---- stage X[cb*32 .. +32) rows y0-1..y0+2, cols 1..128 (x 0..127) ----
        #pragma unroll
        for (int tt = 0; tt < 2; ++tt) {
            int task = tid + tt * 256;
            int qd = task >> 6;         // ci quad 0..7
            int r = (task >> 4) & 3;    // row 0..3
            int xc = task & 15;         // x chunk of 8
            int yy = y0 - 1 + r;
            int x0 = xc * 8;
            int ci0 = cb * 32 + qd * 4;
            u16x8 v0, v1, v2, v3;
            if (yy >= 0 && yy < 128) {
                const unsigned short* sp;
                if (ci0 < cinA) sp = srcA + ((size_t)b * cinA + ci0) * HW;
                else            sp = srcB + ((size_t)b * cinB + (ci0 - cinA)) * HW;
                sp += yy * 128 + x0;
                v0 = *reinterpret_cast<const u16x8*>(sp);
                v1 = *reinterpret_cast<const u16x8*>(sp + HW);
                v2 = *reinterpret_cast<const u16x8*>(sp + 2 * HW);
                v3 = *reinterpret_cast<const u16x8*>(sp + 3 * HW);
            } else {
                v0 = (u16x8)0; v1 = (u16x8)0; v2 = (u16x8)0; v3 = (u16x8)0;
            }
            int sb = ((qd & 3) << 3) + ((qd >> 2) << 2);
            int rowb = r * 132;
            #pragma unroll
            for (int dx = 0; dx < 8; ++dx) {
                int col = x0 + 1 + dx;
                int sbs = sb ^ (((col >> 1) & 3) << 3);
                u16x4 pk = {v0[dx], v1[dx], v2[dx], v3[dx]};
                *reinterpret_cast<u16x4*>(&xs[(rowb + col) * 32 + sbs]) = pk;
            }
        }
        __syncthreads();
        // ---- 9 K-steps of K=32 ----
        #pragma unroll
        for (int ky = 0; ky < 3; ++ky) {
            #pragma unroll
            for (int kx = 0; kx < 3; ++kx) {
                int ks = cb * 9 + ky * 3 + kx;
                bf16x8 afr[4];
                #pragma unroll
                for (int ct = 0; ct < 4; ++ct)
                    afr[ct] = wp[((size_t)(ks * 4 + ct) << 6) + lane];
                bf16x8 bfr[4];
                int row = wr + ky;
                #pragma unroll
                for (int nt = 0; nt < 4; ++nt) {
                    int col = colb + nt * 16 + kx;
                    int sbs = (qg ^ ((col >> 1) & 3)) << 3;
                    bfr[nt] = *reinterpret_cast<const bf16x8*>(&xs[(row * 132 + col) * 32 + sbs]);
                }
                #pragma unroll
                for (int ct = 0; ct < 4; ++ct)
                    #pragma unroll
                    for (int nt = 0; nt < 4; ++nt)
                        acc[ct][nt] = __builtin_amdgcn_mfma_f32_16x16x32_bf16(afr[ct], bfr[nt], acc[ct][nt], 0, 0, 0);
            }
        }
    }

    // ---- epilogue: out[b][co][y0+wr][col], co = ct*16 + qg*4 + reg ----
    int row_out = y0 + wr;
    #pragma unroll
    for (int ct = 0; ct < 4; ++ct) {
        float4 bi = *reinterpret_cast<const float4*>(bias + ct * 16 + qg * 4);
        #pragma unroll
        for (int nt = 0; nt < 4; ++nt) {
            int col_out = ((w & 1) << 6) + nt * 16 + l15;
            #pragma unroll
            for (int reg = 0; reg < 4; ++reg) {
                int co = ct * 16 + qg * 4 + reg;
                float bv = (reg == 0) ? bi.x : (reg == 1) ? bi.y : (reg == 2) ? bi.z : bi.w;
                float v = fmaxf(acc[ct][nt][reg] + bv, 0.f);
                size_t off = ((size_t)b * outcTot + co) * HW + row_out * 128 + col_out;
                if (OBF16) ((unsigned short*)outp)[off] = f2bf(v);
                else       ((float*)outp)[off] = v;
            }
        }
    }
}

// ---------- launch ----------
extern "C" void kernel_launch(void* const* d_in, const int* in_sizes, int n_in,
                              void* d_out, int out_size, void* d_ws, size_t ws_size,
                              hipStream_t stream) {
    const float* x = (const float*)d_in[0];
    const float* y = (const float*)d_in[1];

    QkvArgs qa;
    for (int q = 0; q < 6; q++) {
        qa.w[q] = (const float*)d_in[2 + 3 * q];
        qa.s[q] = (const float*)d_in[3 + 3 * q];
        qa.b[q] = (const float*)d_in[4 + 3 * q];
    }
    const float* red_w = (const float*)d_in[20];
    const float* red_s = (const float*)d_in[21];
    const float* red_b = (const float*)d_in[22];
    const float* sec_w = (const float*)d_in[23];
    const float* sec_s = (const float*)d_in[24];
    const float* sec_b = (const float*)d_in[25];
    const float* g1 = (const float*)d_in[26];
    const float* g2 = (const float*)d_in[27];
    const float* g3 = (const float*)d_in[28];
    const float* g4 = (const float*)d_in[29];
    const float* sa_r_w = (const float*)d_in[30];
    const float* sa_i_w = (const float*)d_in[31];

    // ---- workspace layout ----
    float* WD = (float*)d_ws;                                  // 512 f
    float* WU = WD + 512;                                      // 512 f
    float* SIG = WU + 512;                                     // 524288 f
    unsigned short* WPKR = (unsigned short*)(SIG + 524288);    // 147456 u16
    unsigned short* WPKS = WPKR + 147456;                      // 110592 u16
    unsigned short* GATT = WPKS + 110592;                      // 16*64*HW u16
    unsigned short* CAT4 = GATT + (size_t)16 * 64 * HW;        // 16*256*HW u16
    unsigned short* SECXY = CAT4;                              // alias: reused after conv_red
    float* RE = (float*)(CAT4 + (size_t)16 * 256 * HW);        // 2,097,152 f
    float* QKV = RE + 2097152;                                 // 6,291,456 f
    float* VT = QKV + 6291456;                                 // 2,097,152 f
    float* REF = VT + 2097152;                                 // 4,194,304 f
    float* MM = RE;                                            // alias (RE dead after k_qkv)

    k_init<<<1, 256, 0, stream>>>(WD, WU);
    k_down<<<2 * 16 * 64, 256, 0, stream>>>(x, y, WD, RE);
    k_qkv<<<6 * 16 * 16, 256, 0, stream>>>(RE, qa, QKV, VT);
    k_attn<<<4 * 16 * 128, 256, 0, stream>>>(QKV, VT, REF);
    k_up<<<4 * 16 * 64, 256, 0, stream>>>(REF, WU, x, y, g1, g2, g3, g4, (__hip_bfloat16*)CAT4);
    k_mm<<<2 * 16 * 8, 256, 0, stream>>>(x, y, MM);
    k_spaconv<<<2 * 16 * 8, 256, 0, stream>>>(MM, sa_r_w, sa_i_w, SIG);
    k_wpack<<<72, 256, 0, stream>>>(red_w, red_s, WPKR, 256);
    k_wpack<<<54, 256, 0, stream>>>(sec_w, sec_s, WPKS, 192);
    // red conv: cat4 (256ch bf16) -> gatt (bf16)
    k_conv<8, true><<<16 * 64, 256, 0, stream>>>(CAT4, 256, CAT4, WPKR, red_b, GATT, 64);
    // now CAT4 region is dead -> write scaled inputs there
    k_scale<<<16384, 256, 0, stream>>>(x, y, SIG, SECXY);
    // sec conv: [gatt | y*(1+sig_i) | x*(1+sig_r)] (192ch) -> out fp32
    k_conv<6, false><<<16 * 64, 256, 0, stream>>>(GATT, 64, SECXY, WPKS, sec_b, d_out, 64);
}

// Round 3
// 878.575 us; speedup vs baseline: 9.8102x; 1.9009x over previous
//
#include <hip/hip_runtime.h>
#include <hip/hip_bf16.h>

// ---------- constants ----------
#define B 16
#define C 64
#define H 128
#define W 128
#define S 32
#define S2 1024
#define HW 16384

typedef __attribute__((ext_vector_type(8))) short bf16x8;
typedef __attribute__((ext_vector_type(4))) float f32x4;
typedef __attribute__((ext_vector_type(8))) unsigned short u16x8;
typedef __attribute__((ext_vector_type(4))) unsigned short u16x4;

static __device__ __forceinline__ unsigned short f2bf(float v) {
    __hip_bfloat16 h = __float2bfloat16(v);
    return *reinterpret_cast<unsigned short*>(&h);
}
static __device__ __forceinline__ float bf2f(unsigned short u) {
    union { unsigned int i; float f; } cv;
    cv.i = ((unsigned int)u) << 16;
    return cv.f;
}

// ---------- Keys cubic kernel (a = -0.5) ----------
__device__ __forceinline__ float keys(float t) {
    t = fabsf(t);
    if (t >= 2.f) return 0.f;
    float t2 = t * t, t3 = t2 * t;
    if (t >= 1.f) return -0.5f * t3 + 2.5f * t2 - 4.f * t + 2.f;
    return 1.5f * t3 - 2.5f * t2 + 1.f;
}

// ---------- kernel 0: precompute resize weights ----------
__global__ void k_init(float* __restrict__ wd, float* __restrict__ wu) {
    int tid = threadIdx.x;
    if (tid < 32) {
        int i = tid;
        float sf = 4.f * i + 1.5f;
        int j0 = 4 * i - 6;
        float w[16];
        float s = 0.f;
        for (int k = 0; k < 16; k++) {
            int j = j0 + k;
            float v = 0.f;
            if (j >= 0 && j < 128) v = keys((sf - (float)j) * 0.25f);
            w[k] = v; s += v;
        }
        float inv = 1.f / s;
        for (int k = 0; k < 16; k++) wd[i * 16 + k] = w[k] * inv;
    } else if (tid >= 64 && tid < 192) {
        int i = tid - 64;
        float sf = 0.25f * i - 0.375f;
        int j0 = (int)floorf(sf) - 1;
        float w[4];
        float s = 0.f;
        for (int k = 0; k < 4; k++) {
            int j = j0 + k;
            float v = 0.f;
            if (j >= 0 && j < 32) v = keys(sf - (float)j);
            w[k] = v; s += v;
        }
        float inv = 1.f / s;
        for (int k = 0; k < 4; k++) wu[i * 4 + k] = w[k] * inv;
    }
}

// ---------- kernel 1: bicubic downsample x,y -> re bf16 [2][B][C][1024] ----------
__global__ void k_down(const float* __restrict__ x, const float* __restrict__ y,
                       const float* __restrict__ wd, unsigned short* __restrict__ re) {
    int bid = blockIdx.x;
    int img = bid >> 10;
    int bc = bid & 1023;
    const float* src = (img ? y : x) + (size_t)bc * HW;
    __shared__ float tmp[32][128];
    __shared__ float wsh[512];
    int tid = threadIdx.x;
    for (int i = tid; i < 512; i += 256) wsh[i] = wd[i];
    __syncthreads();
    for (int idx = tid; idx < 32 * 128; idx += 256) {
        int oy = idx >> 7, xx = idx & 127;
        int j0 = 4 * oy - 6;
        float acc = 0.f;
        #pragma unroll
        for (int k = 0; k < 16; k++) {
            int j = j0 + k;
            if (j >= 0 && j < 128) acc += wsh[oy * 16 + k] * src[j * 128 + xx];
        }
        tmp[oy][xx] = acc;
    }
    __syncthreads();
    for (int idx = tid; idx < 1024; idx += 256) {
        int oy = idx >> 5, ox = idx & 31;
        int j0 = 4 * ox - 6;
        float acc = 0.f;
        #pragma unroll
        for (int k = 0; k < 16; k++) {
            int j = j0 + k;
            if (j >= 0 && j < 128) acc += wsh[ox * 16 + k] * tmp[oy][j];
        }
        re[(size_t)bid * 1024 + idx] = f2bf(acc);
    }
}

// ---------- weight pack (BN scale folded) into MFMA A-fragment order ----------
// wpk[ks][ct][lane][j]; ks = cb*9 + ky*3 + kx; A[m=ct*16+(lane&15)][k=(lane>>4)*4+(j&3)+16*(j>>2)]
__global__ void k_wpack(const float* __restrict__ w, const float* __restrict__ s,
                        unsigned short* __restrict__ wpk, int cin) {
    int ks = blockIdx.x;
    int tid = threadIdx.x;
    int lane = tid & 63, ct = tid >> 6;
    int cb = ks / 9, kk = ks % 9;
    int m = ct * 16 + (lane & 15);
    int qq = lane >> 4;
    float sc = s[m];
    u16x8 outv;
    #pragma unroll
    for (int j = 0; j < 8; ++j) {
        int k = qq * 4 + (j & 3) + ((j >> 2) << 4);
        int ci = cb * 32 + k;
        float v = w[((size_t)m * cin + ci) * 9 + kk] * sc;
        outv[j] = f2bf(v);
    }
    *reinterpret_cast<u16x8*>(wpk + ((size_t)(ks * 4 + ct) * 64 + lane) * 8) = outv;
}

// ---------- kernel 2: six QKV 3x3 convs via MFMA, outputs routed per q ----------
struct QkvBias { const float* b[6]; };

__global__ void __launch_bounds__(256) k_qkv2(const unsigned short* __restrict__ re,
                                              const unsigned short* __restrict__ wpkq,
                                              QkvBias bias,
                                              unsigned short* __restrict__ qt,   // [2][16][1024][64]
                                              unsigned short* __restrict__ kn,   // [2][16][64][1024]
                                              unsigned short* __restrict__ vn) { // [2][16][64][1024]
    int bid = blockIdx.x;                 // q*64 + b*4 + quad
    int q = bid >> 6;
    int rem = bid & 63;
    int b = rem >> 2;
    int quad = rem & 3;
    int img = (q < 3) ? 0 : 1;
    const unsigned short* src = re + ((size_t)(img * 16 + b)) * 64 * 1024;
    const bf16x8* wp = reinterpret_cast<const bf16x8*>(wpkq + (size_t)q * 18 * 4 * 64 * 8);
    const float* bptr = bias.b[q];

    int tid = threadIdx.x;
    int lane = tid & 63, w = tid >> 6;
    int l15 = lane & 15, qg = lane >> 4;

    __shared__ __align__(16) unsigned short xs[10 * 34 * 32];

    // zero halo cols 0 and 33 (all rows, all slots); persists across cb loop
    if (tid < 160) {
        int r = tid >> 4;
        int inner = tid & 15;
        int col = (inner >> 3) ? 33 : 0;
        int qd = inner & 7;
        int sbase = ((qd & 3) << 3) + ((qd >> 2) << 2);
        int sbs = sbase ^ ((((col >> 1) & 3)) << 3);
        u16x4 z = {0, 0, 0, 0};
        *reinterpret_cast<u16x4*>(&xs[(r * 34 + col) * 32 + sbs]) = z;
    }

    f32x4 acc[4][4] = {};

    for (int cb = 0; cb < 2; ++cb) {
        __syncthreads();
        // stage rows quad*8-1 .. quad*8+8 (10 rows), ci cb*32..+32
        #pragma unroll
        for (int tt = 0; tt < 2; ++tt) {
            int task = tid + tt * 256;
            if (task < 320) {
                int r = task >> 5;
                int inner = task & 31;
                int qd = inner >> 2, xc = inner & 3;
                int yy = quad * 8 - 1 + r;
                int x0 = xc * 8;
                int ci0 = cb * 32 + qd * 4;
                u16x8 v0, v1, v2, v3;
                if (yy >= 0 && yy < 32) {
                    const unsigned short* sp = src + (size_t)ci0 * 1024 + yy * 32 + x0;
                    v0 = *reinterpret_cast<const u16x8*>(sp);
                    v1 = *reinterpret_cast<const u16x8*>(sp + 1024);
                    v2 = *reinterpret_cast<const u16x8*>(sp + 2048);
                    v3 = *reinterpret_cast<const u16x8*>(sp + 3072);
                } else {
                    v0 = (u16x8)0; v1 = (u16x8)0; v2 = (u16x8)0; v3 = (u16x8)0;
                }
                int sbase = ((qd & 3) << 3) + ((qd >> 2) << 2);
                #pragma unroll
                for (int dx = 0; dx < 8; ++dx) {
                    int col = x0 + 1 + dx;
                    int sbs = sbase ^ (((col >> 1) & 3) << 3);
                    u16x4 pk = {v0[dx], v1[dx], v2[dx], v3[dx]};
                    *reinterpret_cast<u16x4*>(&xs[(r * 34 + col) * 32 + sbs]) = pk;
                }
            }
        }
        __syncthreads();
        #pragma unroll
        for (int ky = 0; ky < 3; ++ky) {
            #pragma unroll
            for (int kx = 0; kx < 3; ++kx) {
                int ksidx = cb * 9 + ky * 3 + kx;
                bf16x8 afr[4];
                #pragma unroll
                for (int ct = 0; ct < 4; ++ct)
                    afr[ct] = wp[((size_t)(ksidx * 4 + ct) << 6) + lane];
                bf16x8 bfr[4];
                #pragma unroll
                for (int nt = 0; nt < 4; ++nt) {
                    int rp = nt >> 1;
                    int col = (nt & 1) * 16 + l15 + kx;
                    int r = w * 2 + rp + ky;
                    int sbs = (qg ^ ((col >> 1) & 3)) << 3;
                    bfr[nt] = *reinterpret_cast<const bf16x8*>(&xs[(r * 34 + col) * 32 + sbs]);
                }
                #pragma unroll
                for (int ct = 0; ct < 4; ++ct)
                    #pragma unroll
                    for (int nt = 0; nt < 4; ++nt)
                        acc[ct][nt] = __builtin_amdgcn_mfma_f32_16x16x32_bf16(afr[ct], bfr[nt], acc[ct][nt], 0, 0, 0);
            }
        }
    }

    // epilogue
    bool isQ = (q == 0 || q == 3);
    int pair = (q < 3) ? 0 : 1;
    unsigned short* qto = qt + ((size_t)(pair * 16 + b)) * 1024 * 64;
    unsigned short* nat = ((q == 1 || q == 4) ? kn : vn) + ((size_t)(pair * 16 + b)) * 64 * 1024;
    #pragma unroll
    for (int ct = 0; ct < 4; ++ct) {
        float4 bi = *reinterpret_cast<const float4*>(bptr + ct * 16 + qg * 4);
        #pragma unroll
        for (int nt = 0; nt < 4; ++nt) {
            int pxl = nt * 16 + l15;
            int rowg = quad * 8 + w * 2 + (pxl >> 5);
            int colg = pxl & 31;
            int px = rowg * 32 + colg;
            #pragma unroll
            for (int reg = 0; reg < 4; ++reg) {
                int co = ct * 16 + qg * 4 + reg;
                float bv = (reg == 0) ? bi.x : (reg == 1) ? bi.y : (reg == 2) ? bi.z : bi.w;
                float v = fmaxf(acc[ct][nt][reg] + bv, 0.f);
                unsigned short bf = f2bf(v);
                if (isQ) qto[(size_t)px * 64 + co] = bf;
                else     nat[(size_t)co * 1024 + px] = bf;
            }
        }
    }
}

// ---------- kernel 2b: DV = RV + IV (bf16) ----------
__global__ void k_dv(const unsigned short* __restrict__ v0, const unsigned short* __restrict__ v1,
                     unsigned short* __restrict__ dv) {
    int i = (blockIdx.x * 256 + threadIdx.x) * 8;
    u16x8 a = *reinterpret_cast<const u16x8*>(v0 + i);
    u16x8 b = *reinterpret_cast<const u16x8*>(v1 + i);
    u16x8 o;
    #pragma unroll
    for (int j = 0; j < 8; ++j) o[j] = f2bf(bf2f(a[j]) + bf2f(b[j]));
    *reinterpret_cast<u16x8*>(dv + i) = o;
}

// ---------- kernel 3: MFMA attention ----------
// Computes S^T = QT x K (m=t, n=s); softmax over t is lane-local; P stays in
// registers and is re-used bit-exactly as the PV B-operand (k=t, n=s).
__global__ void __launch_bounds__(256) k_attn2(
    const unsigned short* __restrict__ QT0, const unsigned short* __restrict__ QT1,
    const unsigned short* __restrict__ K0, const unsigned short* __restrict__ K1,
    const unsigned short* __restrict__ V0, const unsigned short* __restrict__ V1,
    const unsigned short* __restrict__ DV, float* __restrict__ ref) {
    int bid = blockIdx.x;                  // a*1024 + b*64 + stile
    int a = bid >> 10;
    int b = (bid >> 6) & 15;
    int stile = bid & 63;
    int s0 = stile * 16;
    const unsigned short* QT = ((a == 0 || a == 2) ? QT0 : QT1) + (size_t)b * 1024 * 64;
    const unsigned short* K  = ((a == 0 || a == 3) ? K0 : K1) + (size_t)b * 64 * 1024;
    const unsigned short* V  = (a < 2 ? DV : (a == 2 ? V0 : V1)) + (size_t)b * 64 * 1024;

    __shared__ unsigned short ks[64 * 16];
    __shared__ float mxw[4][16];
    __shared__ float smw[4][16];
    __shared__ float rbuf[4][64 * 16];

    int tid = threadIdx.x;
    int lane = tid & 63, w = tid >> 6;
    int l15 = lane & 15, qg = lane >> 4;

    // stage K tile [64 c][16 s]
    {
        int c = tid & 63, sg = tid >> 6;
        u16x4 kv = *reinterpret_cast<const u16x4*>(K + c * 1024 + s0 + sg * 4);
        *reinterpret_cast<u16x4*>(&ks[c * 16 + sg * 4]) = kv;
    }
    __syncthreads();

    // ---- QK^T (S^T): acc[mf] holds t = w*256 + mf*16 + qg*4 + reg, s = s0 + l15 ----
    f32x4 acc[16] = {};
    #pragma unroll
    for (int kb = 0; kb < 2; ++kb) {
        bf16x8 bk;
        #pragma unroll
        for (int j = 0; j < 8; ++j) {
            int c = kb * 32 + qg * 4 + (j & 3) + 16 * (j >> 2);
            bk[j] = (short)ks[c * 16 + l15];
        }
        #pragma unroll
        for (int mf = 0; mf < 16; ++mf) {
            const unsigned short* qrow = QT + (size_t)(w * 256 + mf * 16 + l15) * 64 + kb * 32 + qg * 4;
            u16x4 a0 = *reinterpret_cast<const u16x4*>(qrow);
            u16x4 a1 = *reinterpret_cast<const u16x4*>(qrow + 16);
            bf16x8 af;
            #pragma unroll
            for (int j = 0; j < 4; ++j) { af[j] = (short)a0[j]; af[4 + j] = (short)a1[j]; }
            acc[mf] = __builtin_amdgcn_mfma_f32_16x16x32_bf16(af, bk, acc[mf], 0, 0, 0);
        }
    }

    // ---- softmax over t (per s-row) ----
    float mx = -1e30f;
    #pragma unroll
    for (int mf = 0; mf < 16; ++mf)
        #pragma unroll
        for (int r = 0; r < 4; ++r) mx = fmaxf(mx, acc[mf][r]);
    mx = fmaxf(mx, __shfl_xor(mx, 16));
    mx = fmaxf(mx, __shfl_xor(mx, 32));
    if (qg == 0) mxw[w][l15] = mx;
    __syncthreads();
    float M = fmaxf(fmaxf(mxw[0][l15], mxw[1][l15]), fmaxf(mxw[2][l15], mxw[3][l15]));
    float sm = 0.f;
    #pragma unroll
    for (int mf = 0; mf < 16; ++mf)
        #pragma unroll
        for (int r = 0; r < 4; ++r) {
            float e = __builtin_amdgcn_exp2f((acc[mf][r] - M) * 1.4426950408889634f);
            acc[mf][r] = e;
            sm += e;
        }
    sm += __shfl_xor(sm, 16);
    sm += __shfl_xor(sm, 32);
    if (qg == 0) smw[w][l15] = sm;
    __syncthreads();
    float inv = 1.f / (smw[0][l15] + smw[1][l15] + smw[2][l15] + smw[3][l15]);

    // ---- PV: pacc[mf] = R[c = mf*16 + qg*4 + reg][s = s0 + l15] partial over t-quadrant ----
    f32x4 pacc[4] = {};
    #pragma unroll
    for (int kk = 0; kk < 8; ++kk) {
        bf16x8 bp;
        #pragma unroll
        for (int j = 0; j < 4; ++j) bp[j] = (short)f2bf(acc[2 * kk][j]);
        #pragma unroll
        for (int j = 0; j < 4; ++j) bp[4 + j] = (short)f2bf(acc[2 * kk + 1][j]);
        #pragma unroll
        for (int mf = 0; mf < 4; ++mf) {
            const unsigned short* vrow = V + (size_t)(mf * 16 + l15) * 1024 + w * 256 + kk * 32 + qg * 4;
            u16x4 a0 = *reinterpret_cast<const u16x4*>(vrow);
            u16x4 a1 = *reinterpret_cast<const u16x4*>(vrow + 16);
            bf16x8 af;
            #pragma unroll
            for (int j = 0; j < 4; ++j) { af[j] = (short)a0[j]; af[4 + j] = (short)a1[j]; }
            pacc[mf] = __builtin_amdgcn_mfma_f32_16x16x32_bf16(af, bp, pacc[mf], 0, 0, 0);
        }
    }
    #pragma unroll
    for (int mf = 0; mf < 4; ++mf)
        #pragma unroll
        for (int r = 0; r < 4; ++r)
            rbuf[w][(mf * 16 + qg * 4 + r) * 16 + l15] = pacc[mf][r] * inv;
    __syncthreads();

    // ---- cross-wave reduce + write REF[a][b][c][s0..s0+16) ----
    {
        int c = tid >> 2, sg = tid & 3;
        f32x4 o;
        #pragma unroll
        for (int k2 = 0; k2 < 4; ++k2) {
            int idx = c * 16 + sg * 4 + k2;
            o[k2] = rbuf[0][idx] + rbuf[1][idx] + rbuf[2][idx] + rbuf[3][idx];
        }
        *reinterpret_cast<f32x4*>(ref + (((size_t)a * 16 + b) * 64 + c) * 1024 + s0 + sg * 4) = o;
    }
}

// ---------- kernel 4: bicubic upsample + g*refine + orig -> cat4 (bf16) ----------
__global__ void k_up(const float* __restrict__ ref, const float* __restrict__ wu,
                     const float* __restrict__ x, const float* __restrict__ y,
                     const float* __restrict__ g1, const float* __restrict__ g2,
                     const float* __restrict__ g3, const float* __restrict__ g4,
                     __hip_bfloat16* __restrict__ cat4) {
    int bid = blockIdx.x;
    int a = bid >> 10;
    int rem = bid & 1023;
    int b = rem >> 6, c = rem & 63;
    const float* src = ref + (size_t)bid * 1024;
    const float* orig = ((a == 0 || a == 3) ? x : y) + (size_t)(b * 64 + c) * HW;
    float gv = (a == 0 ? g1 : a == 1 ? g2 : a == 2 ? g3 : g4)[0];
    __shared__ float rch[1024];
    __shared__ float tmp[128][32];
    __shared__ float wsh[512];
    int tid = threadIdx.x;
    for (int i = tid; i < 512; i += 256) wsh[i] = wu[i];
    for (int i = tid; i < 1024; i += 256) rch[i] = src[i];
    __syncthreads();
    for (int idx = tid; idx < 128 * 32; idx += 256) {
        int oy = idx >> 5, xx = idx & 31;
        float sf = 0.25f * oy - 0.375f;
        int j0 = (int)floorf(sf) - 1;
        float acc = 0.f;
        #pragma unroll
        for (int k = 0; k < 4; k++) {
            int j = j0 + k;
            if (j >= 0 && j < 32) acc += wsh[oy * 4 + k] * rch[j * 32 + xx];
        }
        tmp[oy][xx] = acc;
    }
    __syncthreads();
    size_t obase = ((size_t)b * 256 + a * 64 + c) * HW;
    for (int idx = tid; idx < HW; idx += 256) {
        int oy = idx >> 7, ox = idx & 127;
        float sf = 0.25f * ox - 0.375f;
        int j0 = (int)floorf(sf) - 1;
        float acc = 0.f;
        #pragma unroll
        for (int k = 0; k < 4; k++) {
            int j = j0 + k;
            if (j >= 0 && j < 32) acc += wsh[ox * 4 + k] * tmp[oy][j];
        }
        float v = gv * acc + orig[idx];
        cat4[obase + idx] = __float2bfloat16(v);
    }
}

// ---------- kernel 5: channel mean/max ----------
__global__ void k_mm(const float* __restrict__ x, const float* __restrict__ y,
                     float* __restrict__ mm) {
    int bid = blockIdx.x;
    int img = bid >> 7;
    int rem = bid & 127;
    int b = rem >> 3;
    int chunk = rem & 7;
    const float* src = (img ? y : x) + (size_t)b * 64 * HW;
    int tid = threadIdx.x;
    size_t base = ((size_t)(img * 16 + b)) * 2 * HW;
    for (int i = 0; i < 8; i++) {
        int px = chunk * 2048 + i * 256 + tid;
        float s = 0.f, mx = -1e30f;
        for (int c = 0; c < 64; c++) {
            float v = src[(size_t)c * HW + px];
            s += v;
            mx = fmaxf(mx, v);
        }
        mm[base + px] = s * (1.f / 64.f);
        mm[base + HW + px] = mx;
    }
}

// ---------- kernel 6: spatial-attention conv + sigmoid ----------
__global__ void k_spaconv(const float* __restrict__ mm, const float* __restrict__ saw_r,
                          const float* __restrict__ saw_i, float* __restrict__ sig) {
    int bid = blockIdx.x;
    int img = bid >> 7;
    int rem = bid & 127;
    int b = rem >> 3;
    int chunk = rem & 7;
    const float* w = img ? saw_i : saw_r;
    __shared__ float wsh[18];
    if (threadIdx.x < 18) wsh[threadIdx.x] = w[threadIdx.x];
    __syncthreads();
    const float* m0 = mm + ((size_t)(img * 16 + b)) * 2 * HW;
    for (int i = 0; i < 8; i++) {
        int px = chunk * 2048 + i * 256 + threadIdx.x;
        int yy = px >> 7, xx = px & 127;
        float acc = 0.f;
        #pragma unroll
        for (int ch = 0; ch < 2; ch++) {
            const float* m = m0 + (size_t)ch * HW;
            #pragma unroll
            for (int dy = 0; dy < 3; dy++)
                #pragma unroll
                for (int dx = 0; dx < 3; dx++) {
                    int iy = yy + dy - 1, ix = xx + dx - 1;
                    if (iy >= 0 && iy < 128 && ix >= 0 && ix < 128)
                        acc += wsh[ch * 9 + dy * 3 + dx] * m[iy * 128 + ix];
                }
        }
        sig[((size_t)(img * 16 + b)) * HW + px] = 1.f / (1.f + expf(-acc));
    }
}

// ---------- kernel 8: scale inputs for sec conv ----------
__global__ void k_scale(const float* __restrict__ x, const float* __restrict__ y,
                        const float* __restrict__ sig, unsigned short* __restrict__ sxy) {
    int gid = blockIdx.x * 256 + threadIdx.x;
    int part = gid >> 21;
    int b = (gid >> 17) & 15;
    int c = (gid >> 11) & 63;
    int t8 = gid & 2047;
    int px = t8 * 8;
    const float* src = (part ? x : y) + ((size_t)b * 64 + c) * HW + px;
    const float* sg = sig + ((size_t)((part ? 0 : 16) + b)) * HW + px;
    u16x8 o;
    #pragma unroll
    for (int j = 0; j < 8; ++j) o[j] = f2bf(src[j] * (1.f + sg[j]));
    *reinterpret_cast<u16x8*>(sxy + ((size_t)b * 128 + part * 64 + c) * HW + px) = o;
}

// ---------- kernel 9: 3x3 conv via MFMA implicit GEMM (128x128 images) ----------
template<int CIBLKS, bool OBF16>
__global__ void __launch_bounds__(256) k_conv(const unsigned short* __restrict__ srcA, int cinA,
                                              const unsigned short* __restrict__ srcB,
                                              const unsigned short* __restrict__ wpk,
                                              const float* __restrict__ bias,
                                              void* __restrict__ outp, int outcTot) {
    const int CIN = CIBLKS * 32;
    const int cinB = CIN - cinA;
    int bid = blockIdx.x;
    int b = bid >> 6, rp = bid & 63;
    int y0 = rp * 2;
    int tid = threadIdx.x;
    int lane = tid & 63, w = tid >> 6;
    int qg = lane >> 4;
    int l15 = lane & 15;

    __shared__ __align__(16) unsigned short xs[4 * 132 * 32];

    f32x4 acc[4][4] = {};

    if (tid < 64) {
        int r = tid >> 4;
        int rem = tid & 15;
        int col = (rem >> 3) ? 129 : 0;
        int qd = rem & 7;
        int sb = ((qd & 3) << 3) + ((qd >> 2) << 2);
        int sbs = sb ^ (((col >> 1) & 3) << 3);
        u16x4 z = {0, 0, 0, 0};
        *reinterpret_cast<u16x4*>(&xs[(r * 132 + col) * 32 + sbs]) = z;
    }

    const bf16x8* wp = reinterpret_cast<const bf16x8*>(wpk);
    int colb = ((w & 1) << 6) + l15;
    int wr = w >> 1;

    for (int cb = 0; cb < CIBLKS; ++cb) {
        __syncthreads();
        #pragma unroll
        for (int tt = 0; tt < 2; ++tt) {
            int task = tid + tt * 256;
            int qd = task >> 6;
            int r = (task >> 4) & 3;
            int xc = task & 15;
            int yy = y0 - 1 + r;
            int x0 = xc * 8;
            int ci0 = cb * 32 + qd * 4;
            u16x8 v0, v1, v2, v3;
            if (yy >= 0 && yy < 128) {
                const unsigned short* sp;
                if (ci0 < cinA) sp = srcA + ((size_t)b * cinA + ci0) * HW;
                else            sp = srcB + ((size_t)b * cinB + (ci0 - cinA)) * HW;
                sp += yy * 128 + x0;
                v0 = *reinterpret_cast<const u16x8*>(sp);
                v1 = *reinterpret_cast<const u16x8*>(sp + HW);
                v2 = *reinterpret_cast<const u16x8*>(sp + 2 * HW);
                v3 = *reinterpret_cast<const u16x8*>(sp + 3 * HW);
            } else {
                v0 = (u16x8)0; v1 = (u16x8)0; v2 = (u16x8)0; v3 = (u16x8)0;
            }
            int sb = ((qd & 3) << 3) + ((qd >> 2) << 2);
            int rowb = r * 132;
            #pragma unroll
            for (int dx = 0; dx < 8; ++dx) {
                int col = x0 + 1 + dx;
                int sbs = sb ^ (((col >> 1) & 3) << 3);
                u16x4 pk = {v0[dx], v1[dx], v2[dx], v3[dx]};
                *reinterpret_cast<u16x4*>(&xs[(rowb + col) * 32 + sbs]) = pk;
            }
        }
        __syncthreads();
        #pragma unroll
        for (int ky = 0; ky < 3; ++ky) {
            #pragma unroll
            for (int kx = 0; kx < 3; ++kx) {
                int ks = cb * 9 + ky * 3 + kx;
                bf16x8 afr[4];
                #pragma unroll
                for (int ct = 0; ct < 4; ++ct)
                    afr[ct] = wp[((size_t)(ks * 4 + ct) << 6) + lane];
                bf16x8 bfr[4];
                int row = wr + ky;
                #pragma unroll
                for (int nt = 0; nt < 4; ++nt) {
                    int col = colb + nt * 16 + kx;
                    int sbs = (qg ^ ((col >> 1) & 3)) << 3;
                    bfr[nt] = *reinterpret_cast<const bf16x8*>(&xs[(row * 132 + col) * 32 + sbs]);
                }
                #pragma unroll
                for (int ct = 0; ct < 4; ++ct)
                    #pragma unroll
                    for (int nt = 0; nt < 4; ++nt)
                        acc[ct][nt] = __builtin_amdgcn_mfma_f32_16x16x32_bf16(afr[ct], bfr[nt], acc[ct][nt], 0, 0, 0);
            }
        }
    }

    int row_out = y0 + wr;
    #pragma unroll
    for (int ct = 0; ct < 4; ++ct) {
        float4 bi = *reinterpret_cast<const float4*>(bias + ct * 16 + qg * 4);
        #pragma unroll
        for (int nt = 0; nt < 4; ++nt) {
            int col_out = ((w & 1) << 6) + nt * 16 + l15;
            #pragma unroll
            for (int reg = 0; reg < 4; ++reg) {
                int co = ct * 16 + qg * 4 + reg;
                float bv = (reg == 0) ? bi.x : (reg == 1) ? bi.y : (reg == 2) ? bi.z : bi.w;
                float v = fmaxf(acc[ct][nt][reg] + bv, 0.f);
                size_t off = ((size_t)b * outcTot + co) * HW + row_out * 128 + col_out;
                if (OBF16) ((unsigned short*)outp)[off] = f2bf(v);
                else       ((float*)outp)[off] = v;
            }
        }
    }
}

// ---------- launch ----------
extern "C" void kernel_launch(void* const* d_in, const int* in_sizes, int n_in,
                              void* d_out, int out_size, void* d_ws, size_t ws_size,
                              hipStream_t stream) {
    const float* x = (const float*)d_in[0];
    const float* y = (const float*)d_in[1];

    const float* qw[6]; const float* qs[6];
    QkvBias qb;
    for (int q = 0; q < 6; q++) {
        qw[q] = (const float*)d_in[2 + 3 * q];
        qs[q] = (const float*)d_in[3 + 3 * q];
        qb.b[q] = (const float*)d_in[4 + 3 * q];
    }
    const float* red_w = (const float*)d_in[20];
    const float* red_s = (const float*)d_in[21];
    const float* red_b = (const float*)d_in[22];
    const float* sec_w = (const float*)d_in[23];
    const float* sec_s = (const float*)d_in[24];
    const float* sec_b = (const float*)d_in[25];
    const float* g1 = (const float*)d_in[26];
    const float* g2 = (const float*)d_in[27];
    const float* g3 = (const float*)d_in[28];
    const float* g4 = (const float*)d_in[29];
    const float* sa_r_w = (const float*)d_in[30];
    const float* sa_i_w = (const float*)d_in[31];

    // ---- workspace layout ----
    float* WD = (float*)d_ws;                       // 512
    float* WU = WD + 512;                           // 512
    float* SIG = WU + 512;                          // 524288
    float* MM = SIG + 524288;                       // 1048576
    float* REF = MM + 1048576;                      // 4194304
    unsigned short* WPKR = (unsigned short*)(REF + 4194304);  // 147456
    unsigned short* WPKS = WPKR + 147456;           // 110592
    unsigned short* WPKQ = WPKS + 110592;           // 221184
    unsigned short* REB = WPKQ + 221184;            // 2097152
    unsigned short* QT  = REB + 2097152;            // 2097152
    unsigned short* KN  = QT + 2097152;             // 2097152
    unsigned short* VN  = KN + 2097152;             // 2097152
    unsigned short* DVb = VN + 2097152;             // 1048576
    unsigned short* GATT = DVb + 1048576;           // 16777216
    unsigned short* CAT4 = GATT + 16777216;         // 67108864
    unsigned short* SECXY = CAT4;                   // alias (after red conv)

    k_init<<<1, 256, 0, stream>>>(WD, WU);
    k_down<<<2 * 16 * 64, 256, 0, stream>>>(x, y, WD, REB);
    for (int q = 0; q < 6; q++)
        k_wpack<<<18, 256, 0, stream>>>(qw[q], qs[q], WPKQ + (size_t)q * 36864, 64);
    k_wpack<<<72, 256, 0, stream>>>(red_w, red_s, WPKR, 256);
    k_wpack<<<54, 256, 0, stream>>>(sec_w, sec_s, WPKS, 192);
    k_qkv2<<<6 * 64, 256, 0, stream>>>(REB, WPKQ, qb, QT, KN, VN);
    k_dv<<<512, 256, 0, stream>>>(VN, VN + 1048576, DVb);
    k_attn2<<<4 * 16 * 64, 256, 0, stream>>>(QT, QT + 1048576, KN, KN + 1048576,
                                             VN, VN + 1048576, DVb, REF);
    k_up<<<4 * 16 * 64, 256, 0, stream>>>(REF, WU, x, y, g1, g2, g3, g4, (__hip_bfloat16*)CAT4);
    k_mm<<<2 * 16 * 8, 256, 0, stream>>>(x, y, MM);
    k_spaconv<<<2 * 16 * 8, 256, 0, stream>>>(MM, sa_r_w, sa_i_w, SIG);
    k_conv<8, true><<<16 * 64, 256, 0, stream>>>(CAT4, 256, CAT4, WPKR, red_b, GATT, 64);
    k_scale<<<16384, 256, 0, stream>>>(x, y, SIG, SECXY);
    k_conv<6, false><<<16 * 64, 256, 0, stream>>>(GATT, 64, SECXY, WPKS, sec_b, d_out, 64);
}

// Round 4
// 723.312 us; speedup vs baseline: 11.9160x; 1.2147x over previous
//
#include <hip/hip_runtime.h>
#include <hip/hip_bf16.h>

// ---------- constants ----------
#define B 16
#define C 64
#define H 128
#define W 128
#define S 32
#define S2 1024
#define HW 16384

typedef __attribute__((ext_vector_type(8))) short bf16x8;
typedef __attribute__((ext_vector_type(4))) float f32x4;
typedef __attribute__((ext_vector_type(8))) unsigned short u16x8;
typedef __attribute__((ext_vector_type(4))) unsigned short u16x4;

static __device__ __forceinline__ unsigned short f2bf(float v) {
    __hip_bfloat16 h = __float2bfloat16(v);
    return *reinterpret_cast<unsigned short*>(&h);
}
static __device__ __forceinline__ float bf2f(unsigned short u) {
    union { unsigned int i; float f; } cv;
    cv.i = ((unsigned int)u) << 16;
    return cv.f;
}

// ---------- Keys cubic kernel (a = -0.5) ----------
__device__ __forceinline__ float keys(float t) {
    t = fabsf(t);
    if (t >= 2.f) return 0.f;
    float t2 = t * t, t3 = t2 * t;
    if (t >= 1.f) return -0.5f * t3 + 2.5f * t2 - 4.f * t + 2.f;
    return 1.5f * t3 - 2.5f * t2 + 1.f;
}

// ---------- kernel 0: precompute resize weights ----------
__global__ void k_init(float* __restrict__ wd, float* __restrict__ wu) {
    int tid = threadIdx.x;
    if (tid < 32) {
        int i = tid;
        float sf = 4.f * i + 1.5f;
        int j0 = 4 * i - 6;
        float w[16];
        float s = 0.f;
        for (int k = 0; k < 16; k++) {
            int j = j0 + k;
            float v = 0.f;
            if (j >= 0 && j < 128) v = keys((sf - (float)j) * 0.25f);
            w[k] = v; s += v;
        }
        float inv = 1.f / s;
        for (int k = 0; k < 16; k++) wd[i * 16 + k] = w[k] * inv;
    } else if (tid >= 64 && tid < 192) {
        int i = tid - 64;
        float sf = 0.25f * i - 0.375f;
        int j0 = (int)floorf(sf) - 1;
        float w[4];
        float s = 0.f;
        for (int k = 0; k < 4; k++) {
            int j = j0 + k;
            float v = 0.f;
            if (j >= 0 && j < 32) v = keys(sf - (float)j);
            w[k] = v; s += v;
        }
        float inv = 1.f / s;
        for (int k = 0; k < 4; k++) wu[i * 4 + k] = w[k] * inv;
    }
}

// ---------- kernel 1: bicubic downsample x,y -> re bf16 [2][B][C][1024] ----------
__global__ void k_down(const float* __restrict__ x, const float* __restrict__ y,
                       const float* __restrict__ wd, unsigned short* __restrict__ re) {
    int bid = blockIdx.x;
    int img = bid >> 10;
    int bc = bid & 1023;
    const float* src = (img ? y : x) + (size_t)bc * HW;
    __shared__ float tmp[32][128];
    __shared__ float wsh[512];
    int tid = threadIdx.x;
    for (int i = tid; i < 512; i += 256) wsh[i] = wd[i];
    __syncthreads();
    for (int idx = tid; idx < 32 * 128; idx += 256) {
        int oy = idx >> 7, xx = idx & 127;
        int j0 = 4 * oy - 6;
        float acc = 0.f;
        #pragma unroll
        for (int k = 0; k < 16; k++) {
            int j = j0 + k;
            if (j >= 0 && j < 128) acc += wsh[oy * 16 + k] * src[j * 128 + xx];
        }
        tmp[oy][xx] = acc;
    }
    __syncthreads();
    for (int idx = tid; idx < 1024; idx += 256) {
        int oy = idx >> 5, ox = idx & 31;
        int j0 = 4 * ox - 6;
        float acc = 0.f;
        #pragma unroll
        for (int k = 0; k < 16; k++) {
            int j = j0 + k;
            if (j >= 0 && j < 128) acc += wsh[ox * 16 + k] * tmp[oy][j];
        }
        re[(size_t)bid * 1024 + idx] = f2bf(acc);
    }
}

// ---------- weight pack (BN scale folded) into MFMA A-fragment order ----------
__global__ void k_wpack(const float* __restrict__ w, const float* __restrict__ s,
                        unsigned short* __restrict__ wpk, int cin) {
    int ks = blockIdx.x;
    int tid = threadIdx.x;
    int lane = tid & 63, ct = tid >> 6;
    int cb = ks / 9, kk = ks % 9;
    int m = ct * 16 + (lane & 15);
    int qq = lane >> 4;
    float sc = s[m];
    u16x8 outv;
    #pragma unroll
    for (int j = 0; j < 8; ++j) {
        int k = qq * 4 + (j & 3) + ((j >> 2) << 4);
        int ci = cb * 32 + k;
        float v = w[((size_t)m * cin + ci) * 9 + kk] * sc;
        outv[j] = f2bf(v);
    }
    *reinterpret_cast<u16x8*>(wpk + ((size_t)(ks * 4 + ct) * 64 + lane) * 8) = outv;
}

// ---------- kernel 2: six QKV 3x3 convs via MFMA, outputs routed per q ----------
// Q (q=0,3) and K (q=1,4) -> px-major [px][64c]; V (q=2,5) -> co-major [64c][px]
struct QkvBias { const float* b[6]; };

__global__ void __launch_bounds__(256) k_qkv2(const unsigned short* __restrict__ re,
                                              const unsigned short* __restrict__ wpkq,
                                              QkvBias bias,
                                              unsigned short* __restrict__ qt,
                                              unsigned short* __restrict__ kt,
                                              unsigned short* __restrict__ vn) {
    int bid = blockIdx.x;                 // q*64 + b*4 + quad
    int q = bid >> 6;
    int rem = bid & 63;
    int b = rem >> 2;
    int quad = rem & 3;
    int img = (q < 3) ? 0 : 1;
    const unsigned short* src = re + ((size_t)(img * 16 + b)) * 64 * 1024;
    const bf16x8* wp = reinterpret_cast<const bf16x8*>(wpkq + (size_t)q * 18 * 4 * 64 * 8);
    const float* bptr = bias.b[q];

    int tid = threadIdx.x;
    int lane = tid & 63, w = tid >> 6;
    int l15 = lane & 15, qg = lane >> 4;

    __shared__ __align__(16) unsigned short xs[10 * 34 * 32];

    if (tid < 160) {
        int r = tid >> 4;
        int inner = tid & 15;
        int col = (inner >> 3) ? 33 : 0;
        int qd = inner & 7;
        int sbase = ((qd & 3) << 3) + ((qd >> 2) << 2);
        int sbs = sbase ^ ((((col >> 1) & 3)) << 3);
        u16x4 z = {0, 0, 0, 0};
        *reinterpret_cast<u16x4*>(&xs[(r * 34 + col) * 32 + sbs]) = z;
    }

    f32x4 acc[4][4] = {};

    for (int cb = 0; cb < 2; ++cb) {
        __syncthreads();
        #pragma unroll
        for (int tt = 0; tt < 2; ++tt) {
            int task = tid + tt * 256;
            if (task < 320) {
                int r = task >> 5;
                int inner = task & 31;
                int qd = inner >> 2, xc = inner & 3;
                int yy = quad * 8 - 1 + r;
                int x0 = xc * 8;
                int ci0 = cb * 32 + qd * 4;
                u16x8 v0, v1, v2, v3;
                if (yy >= 0 && yy < 32) {
                    const unsigned short* sp = src + (size_t)ci0 * 1024 + yy * 32 + x0;
                    v0 = *reinterpret_cast<const u16x8*>(sp);
                    v1 = *reinterpret_cast<const u16x8*>(sp + 1024);
                    v2 = *reinterpret_cast<const u16x8*>(sp + 2048);
                    v3 = *reinterpret_cast<const u16x8*>(sp + 3072);
                } else {
                    v0 = (u16x8)0; v1 = (u16x8)0; v2 = (u16x8)0; v3 = (u16x8)0;
                }
                int sbase = ((qd & 3) << 3) + ((qd >> 2) << 2);
                #pragma unroll
                for (int dx = 0; dx < 8; ++dx) {
                    int col = x0 + 1 + dx;
                    int sbs = sbase ^ (((col >> 1) & 3) << 3);
                    u16x4 pk = {v0[dx], v1[dx], v2[dx], v3[dx]};
                    *reinterpret_cast<u16x4*>(&xs[(r * 34 + col) * 32 + sbs]) = pk;
                }
            }
        }
        __syncthreads();
        #pragma unroll
        for (int ky = 0; ky < 3; ++ky) {
            #pragma unroll
            for (int kx = 0; kx < 3; ++kx) {
                int ksidx = cb * 9 + ky * 3 + kx;
                bf16x8 afr[4];
                #pragma unroll
                for (int ct = 0; ct < 4; ++ct)
                    afr[ct] = wp[((size_t)(ksidx * 4 + ct) << 6) + lane];
                bf16x8 bfr[4];
                #pragma unroll
                for (int nt = 0; nt < 4; ++nt) {
                    int rp = nt >> 1;
                    int col = (nt & 1) * 16 + l15 + kx;
                    int r = w * 2 + rp + ky;
                    int sbs = (qg ^ ((col >> 1) & 3)) << 3;
                    bfr[nt] = *reinterpret_cast<const bf16x8*>(&xs[(r * 34 + col) * 32 + sbs]);
                }
                #pragma unroll
                for (int ct = 0; ct < 4; ++ct)
                    #pragma unroll
                    for (int nt = 0; nt < 4; ++nt)
                        acc[ct][nt] = __builtin_amdgcn_mfma_f32_16x16x32_bf16(afr[ct], bfr[nt], acc[ct][nt], 0, 0, 0);
            }
        }
    }

    // epilogue
    int pair = (q < 3) ? 0 : 1;
    bool isV = (q == 2 || q == 5);
    unsigned short* dst;
    if (q == 0 || q == 3)      dst = qt + ((size_t)(pair * 16 + b)) * 65536;
    else if (q == 1 || q == 4) dst = kt + ((size_t)(pair * 16 + b)) * 65536;
    else                       dst = vn + ((size_t)(pair * 16 + b)) * 65536;
    #pragma unroll
    for (int ct = 0; ct < 4; ++ct) {
        float4 bi = *reinterpret_cast<const float4*>(bptr + ct * 16 + qg * 4);
        #pragma unroll
        for (int nt = 0; nt < 4; ++nt) {
            int pxl = nt * 16 + l15;
            int rowg = quad * 8 + w * 2 + (pxl >> 5);
            int colg = pxl & 31;
            int px = rowg * 32 + colg;
            #pragma unroll
            for (int reg = 0; reg < 4; ++reg) {
                int co = ct * 16 + qg * 4 + reg;
                float bv = (reg == 0) ? bi.x : (reg == 1) ? bi.y : (reg == 2) ? bi.z : bi.w;
                float v = fmaxf(acc[ct][nt][reg] + bv, 0.f);
                unsigned short bf = f2bf(v);
                if (isV) dst[(size_t)co * 1024 + px] = bf;
                else     dst[(size_t)px * 64 + co] = bf;
            }
        }
    }
}

// ---------- pack Q/K (px-major [1024][64]) into MFMA fragment order ----------
// dst entry fi = tf*2+kb : [64 lanes][8]; elem j: src[(tf*16+l15)*64 + kb*32 + qg*4 + (j&3) + 16*(j>>2)]
__global__ void k_packa(const unsigned short* __restrict__ qt,
                        const unsigned short* __restrict__ kt,
                        unsigned short* __restrict__ qtf,
                        unsigned short* __restrict__ ktf) {
    int bid = blockIdx.x;            // tsel*128 + b*8 + seg
    int tsel = bid >> 7;
    int b = (bid >> 3) & 15;
    int seg = bid & 7;
    int tid = threadIdx.x;
    int lane = tid & 63, w = tid >> 6;
    int l15 = lane & 15, qg = lane >> 4;
    const unsigned short* src = (tsel < 2 ? qt : kt) + ((size_t)((tsel & 1) * 16 + b)) * 65536;
    unsigned short* dst = (tsel < 2 ? qtf : ktf) + ((size_t)((tsel & 1) * 16 + b)) * 65536;
    #pragma unroll
    for (int it = 0; it < 4; ++it) {
        int fi = seg * 16 + it * 4 + w;
        int tf = fi >> 1, kb = fi & 1;
        const unsigned short* row = src + (size_t)(tf * 16 + l15) * 64 + kb * 32 + qg * 4;
        u16x4 a0 = *reinterpret_cast<const u16x4*>(row);
        u16x4 a1 = *reinterpret_cast<const u16x4*>(row + 16);
        u16x8 o;
        #pragma unroll
        for (int j = 0; j < 4; ++j) { o[j] = a0[j]; o[4 + j] = a1[j]; }
        *reinterpret_cast<u16x8*>(dst + (size_t)fi * 512 + lane * 8) = o;
    }
}

// ---------- pack V (co-major [64][1024]) into fragment order; also builds DV=RV+IV ----------
// vf[v][b] entry fi = cf*32 + tq : [64 lanes][8]; elem j: V[cf*16+l15][tq*32 + qg*4 + (j&3) + 16*(j>>2)]
__global__ void k_packv(const unsigned short* __restrict__ vn,
                        unsigned short* __restrict__ vf) {
    int bid = blockIdx.x;            // b*8 + seg
    int b = bid >> 3;
    int seg = bid & 7;
    int tid = threadIdx.x;
    int lane = tid & 63, w = tid >> 6;
    int l15 = lane & 15, qg = lane >> 4;
    const unsigned short* rv = vn + (size_t)b * 65536;
    const unsigned short* iv = vn + (size_t)(16 + b) * 65536;
    #pragma unroll
    for (int it = 0; it < 4; ++it) {
        int fi = seg * 16 + it * 4 + w;
        int cf = fi >> 5, tq = fi & 31;
        int c = cf * 16 + l15;
        size_t roff = (size_t)c * 1024 + tq * 32 + qg * 4;
        u16x4 r0 = *reinterpret_cast<const u16x4*>(rv + roff);
        u16x4 r1 = *reinterpret_cast<const u16x4*>(rv + roff + 16);
        u16x4 i0 = *reinterpret_cast<const u16x4*>(iv + roff);
        u16x4 i1 = *reinterpret_cast<const u16x4*>(iv + roff + 16);
        u16x8 orv, oiv, odv;
        #pragma unroll
        for (int j = 0; j < 4; ++j) {
            orv[j] = r0[j]; orv[4 + j] = r1[j];
            oiv[j] = i0[j]; oiv[4 + j] = i1[j];
            odv[j] = f2bf(bf2f(r0[j]) + bf2f(i0[j]));
            odv[4 + j] = f2bf(bf2f(r1[j]) + bf2f(i1[j]));
        }
        size_t eoff = ((size_t)b * 128 + fi) * 512 + lane * 8;
        *reinterpret_cast<u16x8*>(vf + eoff) = orv;
        *reinterpret_cast<u16x8*>(vf + 1048576 + eoff) = oiv;
        *reinterpret_cast<u16x8*>(vf + 2097152 + eoff) = odv;
    }
}

// ---------- kernel 3: MFMA attention, all operands in fragment layout ----------
__global__ void __launch_bounds__(256) k_attn3(const unsigned short* __restrict__ QTF,
                                               const unsigned short* __restrict__ KTF,
                                               const unsigned short* __restrict__ VF,
                                               float* __restrict__ ref) {
    int bid = blockIdx.x;                  // a*1024 + b*64 + stile
    int a = bid >> 10;
    int b = (bid >> 6) & 15;
    int stile = bid & 63;
    int qsel = (a == 0 || a == 2) ? 0 : 1;
    int ksel = (a == 0 || a == 3) ? 0 : 1;
    int vsel = (a < 2) ? 2 : (a == 2 ? 0 : 1);

    int tid = threadIdx.x;
    int lane = tid & 63, w = tid >> 6;
    int l15 = lane & 15, qg = lane >> 4;

    const bf16x8* qf = reinterpret_cast<const bf16x8*>(QTF) + ((size_t)(qsel * 16 + b) * 128) * 64;
    const bf16x8* kf = reinterpret_cast<const bf16x8*>(KTF) + ((size_t)(ksel * 16 + b) * 128) * 64;
    const bf16x8* vfb = reinterpret_cast<const bf16x8*>(VF) + ((size_t)(vsel * 16 + b) * 128) * 64;

    __shared__ float mxw[4][16];
    __shared__ float smw[4][16];
    __shared__ float rbuf[4][64 * 16];

    // ---- QK^T (S^T): acc[mf] holds t = w*256 + mf*16 + qg*4 + reg, s = stile*16 + l15 ----
    bf16x8 bk0 = kf[(size_t)(stile * 2 + 0) * 64 + lane];
    bf16x8 bk1 = kf[(size_t)(stile * 2 + 1) * 64 + lane];
    f32x4 acc[16] = {};
    #pragma unroll
    for (int mf = 0; mf < 16; ++mf) {
        int tf = w * 16 + mf;
        bf16x8 a0 = qf[(size_t)(tf * 2 + 0) * 64 + lane];
        bf16x8 a1 = qf[(size_t)(tf * 2 + 1) * 64 + lane];
        acc[mf] = __builtin_amdgcn_mfma_f32_16x16x32_bf16(a0, bk0, acc[mf], 0, 0, 0);
        acc[mf] = __builtin_amdgcn_mfma_f32_16x16x32_bf16(a1, bk1, acc[mf], 0, 0, 0);
    }

    // ---- softmax over t (per s-column, lane-local then cross-lane/wave) ----
    float mx = -1e30f;
    #pragma unroll
    for (int mf = 0; mf < 16; ++mf)
        #pragma unroll
        for (int r = 0; r < 4; ++r) mx = fmaxf(mx, acc[mf][r]);
    mx = fmaxf(mx, __shfl_xor(mx, 16));
    mx = fmaxf(mx, __shfl_xor(mx, 32));
    if (qg == 0) mxw[w][l15] = mx;
    __syncthreads();
    float M = fmaxf(fmaxf(mxw[0][l15], mxw[1][l15]), fmaxf(mxw[2][l15], mxw[3][l15]));
    float sm = 0.f;
    #pragma unroll
    for (int mf = 0; mf < 16; ++mf)
        #pragma unroll
        for (int r = 0; r < 4; ++r) {
            float e = __builtin_amdgcn_exp2f((acc[mf][r] - M) * 1.4426950408889634f);
            acc[mf][r] = e;
            sm += e;
        }
    sm += __shfl_xor(sm, 16);
    sm += __shfl_xor(sm, 32);
    if (qg == 0) smw[w][l15] = sm;
    __syncthreads();
    float inv = 1.f / (smw[0][l15] + smw[1][l15] + smw[2][l15] + smw[3][l15]);

    // ---- PV: P (in registers) is bit-exactly the B-operand; V frags coalesced ----
    f32x4 pacc[4] = {};
    #pragma unroll
    for (int kk = 0; kk < 8; ++kk) {
        bf16x8 bp;
        #pragma unroll
        for (int j = 0; j < 4; ++j) {
            bp[j] = (short)f2bf(acc[2 * kk][j]);
            bp[4 + j] = (short)f2bf(acc[2 * kk + 1][j]);
        }
        #pragma unroll
        for (int cf = 0; cf < 4; ++cf) {
            bf16x8 av = vfb[(size_t)(cf * 32 + w * 8 + kk) * 64 + lane];
            pacc[cf] = __builtin_amdgcn_mfma_f32_16x16x32_bf16(av, bp, pacc[cf], 0, 0, 0);
        }
    }
    #pragma unroll
    for (int cf = 0; cf < 4; ++cf)
        #pragma unroll
        for (int r = 0; r < 4; ++r)
            rbuf[w][(cf * 16 + qg * 4 + r) * 16 + l15] = pacc[cf][r] * inv;
    __syncthreads();

    // ---- cross-wave reduce + write REF[a][b][c][s0..s0+16) ----
    {
        int c = tid >> 2, sg = tid & 3;
        f32x4 o;
        #pragma unroll
        for (int k2 = 0; k2 < 4; ++k2) {
            int idx = c * 16 + sg * 4 + k2;
            o[k2] = rbuf[0][idx] + rbuf[1][idx] + rbuf[2][idx] + rbuf[3][idx];
        }
        *reinterpret_cast<f32x4*>(ref + (((size_t)a * 16 + b) * 64 + c) * 1024 + stile * 16 + sg * 4) = o;
    }
}

// ---------- kernel 4: bicubic upsample + g*refine + orig -> cat4 (bf16) ----------
__global__ void k_up(const float* __restrict__ ref, const float* __restrict__ wu,
                     const float* __restrict__ x, const float* __restrict__ y,
                     const float* __restrict__ g1, const float* __restrict__ g2,
                     const float* __restrict__ g3, const float* __restrict__ g4,
                     __hip_bfloat16* __restrict__ cat4) {
    int bid = blockIdx.x;
    int a = bid >> 10;
    int rem = bid & 1023;
    int b = rem >> 6, c = rem & 63;
    const float* src = ref + (size_t)bid * 1024;
    const float* orig = ((a == 0 || a == 3) ? x : y) + (size_t)(b * 64 + c) * HW;
    float gv = (a == 0 ? g1 : a == 1 ? g2 : a == 2 ? g3 : g4)[0];
    __shared__ float rch[1024];
    __shared__ float tmp[128][32];
    __shared__ float wsh[512];
    int tid = threadIdx.x;
    for (int i = tid; i < 512; i += 256) wsh[i] = wu[i];
    for (int i = tid; i < 1024; i += 256) rch[i] = src[i];
    __syncthreads();
    for (int idx = tid; idx < 128 * 32; idx += 256) {
        int oy = idx >> 5, xx = idx & 31;
        float sf = 0.25f * oy - 0.375f;
        int j0 = (int)floorf(sf) - 1;
        float acc = 0.f;
        #pragma unroll
        for (int k = 0; k < 4; k++) {
            int j = j0 + k;
            if (j >= 0 && j < 32) acc += wsh[oy * 4 + k] * rch[j * 32 + xx];
        }
        tmp[oy][xx] = acc;
    }
    __syncthreads();
    size_t obase = ((size_t)b * 256 + a * 64 + c) * HW;
    for (int idx = tid; idx < HW; idx += 256) {
        int oy = idx >> 7, ox = idx & 127;
        float sf = 0.25f * ox - 0.375f;
        int j0 = (int)floorf(sf) - 1;
        float acc = 0.f;
        #pragma unroll
        for (int k = 0; k < 4; k++) {
            int j = j0 + k;
            if (j >= 0 && j < 32) acc += wsh[ox * 4 + k] * tmp[oy][j];
        }
        float v = gv * acc + orig[idx];
        cat4[obase + idx] = __float2bfloat16(v);
    }
}

// ---------- kernel 5: channel mean/max ----------
__global__ void k_mm(const float* __restrict__ x, const float* __restrict__ y,
                     float* __restrict__ mm) {
    int bid = blockIdx.x;
    int img = bid >> 7;
    int rem = bid & 127;
    int b = rem >> 3;
    int chunk = rem & 7;
    const float* src = (img ? y : x) + (size_t)b * 64 * HW;
    int tid = threadIdx.x;
    size_t base = ((size_t)(img * 16 + b)) * 2 * HW;
    for (int i = 0; i < 8; i++) {
        int px = chunk * 2048 + i * 256 + tid;
        float s = 0.f, mx = -1e30f;
        for (int c = 0; c < 64; c++) {
            float v = src[(size_t)c * HW + px];
            s += v;
            mx = fmaxf(mx, v);
        }
        mm[base + px] = s * (1.f / 64.f);
        mm[base + HW + px] = mx;
    }
}

// ---------- kernel 6: spatial-attention conv + sigmoid ----------
__global__ void k_spaconv(const float* __restrict__ mm, const float* __restrict__ saw_r,
                          const float* __restrict__ saw_i, float* __restrict__ sig) {
    int bid = blockIdx.x;
    int img = bid >> 7;
    int rem = bid & 127;
    int b = rem >> 3;
    int chunk = rem & 7;
    const float* w = img ? saw_i : saw_r;
    __shared__ float wsh[18];
    if (threadIdx.x < 18) wsh[threadIdx.x] = w[threadIdx.x];
    __syncthreads();
    const float* m0 = mm + ((size_t)(img * 16 + b)) * 2 * HW;
    for (int i = 0; i < 8; i++) {
        int px = chunk * 2048 + i * 256 + threadIdx.x;
        int yy = px >> 7, xx = px & 127;
        float acc = 0.f;
        #pragma unroll
        for (int ch = 0; ch < 2; ch++) {
            const float* m = m0 + (size_t)ch * HW;
            #pragma unroll
            for (int dy = 0; dy < 3; dy++)
                #pragma unroll
                for (int dx = 0; dx < 3; dx++) {
                    int iy = yy + dy - 1, ix = xx + dx - 1;
                    if (iy >= 0 && iy < 128 && ix >= 0 && ix < 128)
                        acc += wsh[ch * 9 + dy * 3 + dx] * m[iy * 128 + ix];
                }
        }
        sig[((size_t)(img * 16 + b)) * HW + px] = 1.f / (1.f + expf(-acc));
    }
}

// ---------- kernel 8: scale inputs for sec conv ----------
__global__ void k_scale(const float* __restrict__ x, const float* __restrict__ y,
                        const float* __restrict__ sig, unsigned short* __restrict__ sxy) {
    int gid = blockIdx.x * 256 + threadIdx.x;
    int part = gid >> 21;
    int b = (gid >> 17) & 15;
    int c = (gid >> 11) & 63;
    int t8 = gid & 2047;
    int px = t8 * 8;
    const float* src = (part ? x : y) + ((size_t)b * 64 + c) * HW + px;
    const float* sg = sig + ((size_t)((part ? 0 : 16) + b)) * HW + px;
    u16x8 o;
    #pragma unroll
    for (int j = 0; j < 8; ++j) o[j] = f2bf(src[j] * (1.f + sg[j]));
    *reinterpret_cast<u16x8*>(sxy + ((size_t)b * 128 + part * 64 + c) * HW + px) = o;
}

// ---------- kernel 9: 3x3 conv via MFMA implicit GEMM (128x128 images) ----------
template<int CIBLKS, bool OBF16>
__global__ void __launch_bounds__(256) k_conv(const unsigned short* __restrict__ srcA, int cinA,
                                              const unsigned short* __restrict__ srcB,
                                              const unsigned short* __restrict__ wpk,
                                              const float* __restrict__ bias,
                                              void* __restrict__ outp, int outcTot) {
    const int CIN = CIBLKS * 32;
    const int cinB = CIN - cinA;
    int bid = blockIdx.x;
    int b = bid >> 6, rp = bid & 63;
    int y0 = rp * 2;
    int tid = threadIdx.x;
    int lane = tid & 63, w = tid >> 6;
    int qg = lane >> 4;
    int l15 = lane & 15;

    __shared__ __align__(16) unsigned short xs[4 * 132 * 32];

    f32x4 acc[4][4] = {};

    if (tid < 64) {
        int r = tid >> 4;
        int rem = tid & 15;
        int col = (rem >> 3) ? 129 : 0;
        int qd = rem & 7;
        int sb = ((qd & 3) << 3) + ((qd >> 2) << 2);
        int sbs = sb ^ (((col >> 1) & 3) << 3);
        u16x4 z = {0, 0, 0, 0};
        *reinterpret_cast<u16x4*>(&xs[(r * 132 + col) * 32 + sbs]) = z;
    }

    const bf16x8* wp = reinterpret_cast<const bf16x8*>(wpk);
    int colb = ((w & 1) << 6) + l15;
    int wr = w >> 1;

    for (int cb = 0; cb < CIBLKS; ++cb) {
        __syncthreads();
        #pragma unroll
        for (int tt = 0; tt < 2; ++tt) {
            int task = tid + tt * 256;
            int qd = task >> 6;
            int r = (task >> 4) & 3;
            int xc = task & 15;
            int yy = y0 - 1 + r;
            int x0 = xc * 8;
            int ci0 = cb * 32 + qd * 4;
            u16x8 v0, v1, v2, v3;
            if (yy >= 0 && yy < 128) {
                const unsigned short* sp;
                if (ci0 < cinA) sp = srcA + ((size_t)b * cinA + ci0) * HW;
                else            sp = srcB + ((size_t)b * cinB + (ci0 - cinA)) * HW;
                sp += yy * 128 + x0;
                v0 = *reinterpret_cast<const u16x8*>(sp);
                v1 = *reinterpret_cast<const u16x8*>(sp + HW);
                v2 = *reinterpret_cast<const u16x8*>(sp + 2 * HW);
                v3 = *reinterpret_cast<const u16x8*>(sp + 3 * HW);
            } else {
                v0 = (u16x8)0; v1 = (u16x8)0; v2 = (u16x8)0; v3 = (u16x8)0;
            }
            int sb = ((qd & 3) << 3) + ((qd >> 2) << 2);
            int rowb = r * 132;
            #pragma unroll
            for (int dx = 0; dx < 8; ++dx) {
                int col = x0 + 1 + dx;
                int sbs = sb ^ (((col >> 1) & 3) << 3);
                u16x4 pk = {v0[dx], v1[dx], v2[dx], v3[dx]};
                *reinterpret_cast<u16x4*>(&xs[(rowb + col) * 32 + sbs]) = pk;
            }
        }
        __syncthreads();
        #pragma unroll
        for (int ky = 0; ky < 3; ++ky) {
            #pragma unroll
            for (int kx = 0; kx < 3; ++kx) {
                int ks = cb * 9 + ky * 3 + kx;
                bf16x8 afr[4];
                #pragma unroll
                for (int ct = 0; ct < 4; ++ct)
                    afr[ct] = wp[((size_t)(ks * 4 + ct) << 6) + lane];
                bf16x8 bfr[4];
                int row = wr + ky;
                #pragma unroll
                for (int nt = 0; nt < 4; ++nt) {
                    int col = colb + nt * 16 + kx;
                    int sbs = (qg ^ ((col >> 1) & 3)) << 3;
                    bfr[nt] = *reinterpret_cast<const bf16x8*>(&xs[(row * 132 + col) * 32 + sbs]);
                }
                #pragma unroll
                for (int ct = 0; ct < 4; ++ct)
                    #pragma unroll
                    for (int nt = 0; nt < 4; ++nt)
                        acc[ct][nt] = __builtin_amdgcn_mfma_f32_16x16x32_bf16(afr[ct], bfr[nt], acc[ct][nt], 0, 0, 0);
            }
        }
    }

    int row_out = y0 + wr;
    #pragma unroll
    for (int ct = 0; ct < 4; ++ct) {
        float4 bi = *reinterpret_cast<const float4*>(bias + ct * 16 + qg * 4);
        #pragma unroll
        for (int nt = 0; nt < 4; ++nt) {
            int col_out = ((w & 1) << 6) + nt * 16 + l15;
            #pragma unroll
            for (int reg = 0; reg < 4; ++reg) {
                int co = ct * 16 + qg * 4 + reg;
                float bv = (reg == 0) ? bi.x : (reg == 1) ? bi.y : (reg == 2) ? bi.z : bi.w;
                float v = fmaxf(acc[ct][nt][reg] + bv, 0.f);
                size_t off = ((size_t)b * outcTot + co) * HW + row_out * 128 + col_out;
                if (OBF16) ((unsigned short*)outp)[off] = f2bf(v);
                else       ((float*)outp)[off] = v;
            }
        }
    }
}

// ---------- launch ----------
extern "C" void kernel_launch(void* const* d_in, const int* in_sizes, int n_in,
                              void* d_out, int out_size, void* d_ws, size_t ws_size,
                              hipStream_t stream) {
    const float* x = (const float*)d_in[0];
    const float* y = (const float*)d_in[1];

    const float* qw[6]; const float* qs[6];
    QkvBias qb;
    for (int q = 0; q < 6; q++) {
        qw[q] = (const float*)d_in[2 + 3 * q];
        qs[q] = (const float*)d_in[3 + 3 * q];
        qb.b[q] = (const float*)d_in[4 + 3 * q];
    }
    const float* red_w = (const float*)d_in[20];
    const float* red_s = (const float*)d_in[21];
    const float* red_b = (const float*)d_in[22];
    const float* sec_w = (const float*)d_in[23];
    const float* sec_s = (const float*)d_in[24];
    const float* sec_b = (const float*)d_in[25];
    const float* g1 = (const float*)d_in[26];
    const float* g2 = (const float*)d_in[27];
    const float* g3 = (const float*)d_in[28];
    const float* g4 = (const float*)d_in[29];
    const float* sa_r_w = (const float*)d_in[30];
    const float* sa_i_w = (const float*)d_in[31];

    // ---- workspace layout ----
    float* WD = (float*)d_ws;                       // 512
    float* WU = WD + 512;                           // 512
    float* SIG = WU + 512;                          // 524288
    float* MM = SIG + 524288;                       // 1048576
    float* REF = MM + 1048576;                      // 4194304
    unsigned short* WPKR = (unsigned short*)(REF + 4194304);  // 147456
    unsigned short* WPKS = WPKR + 147456;           // 110592
    unsigned short* WPKQ = WPKS + 110592;           // 221184
    unsigned short* REB = WPKQ + 221184;            // 2097152
    unsigned short* QT  = REB + 2097152;            // 2097152  [2][16][1024][64]
    unsigned short* KT  = QT + 2097152;             // 2097152  [2][16][1024][64]
    unsigned short* VN  = KT + 2097152;             // 2097152  [2][16][64][1024]
    unsigned short* GATT = VN + 2097152;            // 16777216
    unsigned short* CAT4 = GATT + 16777216;         // 67108864
    // fragment buffers alias the CAT4 region (dead until k_up runs, which is after attn)
    unsigned short* QTF = CAT4;                     // 2097152
    unsigned short* KTF = CAT4 + 2097152;           // 2097152
    unsigned short* VF  = CAT4 + 4194304;           // 3145728
    unsigned short* SECXY = CAT4;                   // alias (after red conv)

    k_init<<<1, 256, 0, stream>>>(WD, WU);
    k_down<<<2 * 16 * 64, 256, 0, stream>>>(x, y, WD, REB);
    for (int q = 0; q < 6; q++)
        k_wpack<<<18, 256, 0, stream>>>(qw[q], qs[q], WPKQ + (size_t)q * 36864, 64);
    k_wpack<<<72, 256, 0, stream>>>(red_w, red_s, WPKR, 256);
    k_wpack<<<54, 256, 0, stream>>>(sec_w, sec_s, WPKS, 192);
    k_qkv2<<<6 * 64, 256, 0, stream>>>(REB, WPKQ, qb, QT, KT, VN);
    k_packa<<<512, 256, 0, stream>>>(QT, KT, QTF, KTF);
    k_packv<<<128, 256, 0, stream>>>(VN, VF);
    k_attn3<<<4 * 16 * 64, 256, 0, stream>>>(QTF, KTF, VF, REF);
    k_up<<<4 * 16 * 64, 256, 0, stream>>>(REF, WU, x, y, g1, g2, g3, g4, (__hip_bfloat16*)CAT4);
    k_mm<<<2 * 16 * 8, 256, 0, stream>>>(x, y, MM);
    k_spaconv<<<2 * 16 * 8, 256, 0, stream>>>(MM, sa_r_w, sa_i_w, SIG);
    k_conv<8, true><<<16 * 64, 256, 0, stream>>>(CAT4, 256, CAT4, WPKR, red_b, GATT, 64);
    k_scale<<<16384, 256, 0, stream>>>(x, y, SIG, SECXY);
    k_conv<6, false><<<16 * 64, 256, 0, stream>>>(GATT, 64, SECXY, WPKS, sec_b, d_out, 64);
}